// Round 3
// baseline (5620.228 us; speedup 1.0000x reference)
//
#include <hip/hip_runtime.h>
#include <hip/hip_bf16.h>

#define TPB 256

// ================= utility =================
__global__ __launch_bounds__(TPB) void k_zero_int(int* p, int n) {
  int i = blockIdx.x * TPB + threadIdx.x;
  if (i < n) p[i] = 0;
}

__global__ __launch_bounds__(TPB) void k_mask0(const float* __restrict__ mask,
                                               float* __restrict__ m0, int n) {
  int i = blockIdx.x * TPB + threadIdx.x;
  if (i < n) m0[i] = (mask[i] < 0.1f) ? 1.0f : 0.0f;
}

// active-site dilation: window 3 stride 2 pad 1 max-pool
__global__ __launch_bounds__(TPB) void k_downmask(const float* __restrict__ mi,
                                                  float* __restrict__ mo, int Dout) {
  int n = Dout * Dout * Dout;
  int idx = blockIdx.x * TPB + threadIdx.x;
  if (idx >= n) return;
  int Din = Dout * 2;
  int ox = idx % Dout, oy = (idx / Dout) % Dout, oz = idx / (Dout * Dout);
  float v = 0.f;
  for (int kz = 0; kz < 3; kz++) {
    int iz = 2 * oz + kz - 1; if ((unsigned)iz >= (unsigned)Din) continue;
    for (int ky = 0; ky < 3; ky++) {
      int iy = 2 * oy + ky - 1; if ((unsigned)iy >= (unsigned)Din) continue;
      for (int kx = 0; kx < 3; kx++) {
        int ix = 2 * ox + kx - 1; if ((unsigned)ix >= (unsigned)Din) continue;
        v = fmaxf(v, mi[(iz * Din + iy) * Din + ix]);
      }
    }
  }
  mo[idx] = v;
}

__global__ __launch_bounds__(TPB) void k_maskx(const float* __restrict__ x,
                                               const float* __restrict__ m,
                                               float* __restrict__ o,
                                               long total, int vox) {
  long i = blockIdx.x * (long)TPB + threadIdx.x;
  if (i < total) o[i] = x[i] * m[i % vox];
}

// ================= convs (no atomics; split-K writes partials) ==========
// out layout [co][vox]; partial slice blockIdx.y writes outp[y*total + idx]
__global__ __launch_bounds__(TPB) void k_conv3(const float* __restrict__ in,
                                               const float* __restrict__ w,
                                               float* __restrict__ outp,
                                               int Cin, int Cout, int Din, int Dout,
                                               int S, int P, int ciPer) {
  long idx = blockIdx.x * (long)TPB + threadIdx.x;
  int vox = Dout * Dout * Dout;
  long total = (long)Cout * vox;
  if (idx >= total) return;
  int p = (int)(idx % vox);
  int co = (int)(idx / vox);
  int ox = p % Dout, oy = (p / Dout) % Dout, oz = p / (Dout * Dout);
  int ci0 = blockIdx.y * ciPer, ci1 = ci0 + ciPer;
  float acc = 0.f;
  for (int ci = ci0; ci < ci1; ++ci) {
    const float* wp = w + ((long)co * Cin + ci) * 27;
    const float* ip = in + (long)ci * Din * Din * Din;
    for (int kz = 0; kz < 3; kz++) {
      int iz = S * oz + kz - P; if ((unsigned)iz >= (unsigned)Din) continue;
      for (int ky = 0; ky < 3; ky++) {
        int iy = S * oy + ky - P; if ((unsigned)iy >= (unsigned)Din) continue;
        for (int kx = 0; kx < 3; kx++) {
          int ix = S * ox + kx - P; if ((unsigned)ix >= (unsigned)Din) continue;
          acc += ip[(iz * Din + iy) * Din + ix] * wp[(kz * 3 + ky) * 3 + kx];
        }
      }
    }
  }
  outp[(long)blockIdx.y * total + idx] = acc;
}

// transposed conv k=3 s=2 'SAME' (jax conv_transpose, pads (2,1), no flip)
// y[o] taps: o even -> (k=0,i=o/2-1),(k=2,i=o/2);  o odd -> (k=1,i=(o-1)/2)
__global__ __launch_bounds__(TPB) void k_convT(const float* __restrict__ in,
                                               const float* __restrict__ w,
                                               float* __restrict__ outp,
                                               int Cin, int Cout, int Din, int Dout,
                                               int ciPer) {
  long idx = blockIdx.x * (long)TPB + threadIdx.x;
  int vox = Dout * Dout * Dout;
  long total = (long)Cout * vox;
  if (idx >= total) return;
  int p = (int)(idx % vox);
  int co = (int)(idx / vox);
  int ox = p % Dout, oy = (p / Dout) % Dout, oz = p / (Dout * Dout);

  int izs[2], kzs[2], nz = 0;
  int iys[2], kys[2], ny = 0;
  int ixs[2], kxs[2], nx = 0;
  if (oz & 1) { izs[0] = (oz - 1) >> 1; kzs[0] = 1; nz = 1; }
  else { int i0 = (oz >> 1) - 1; if (i0 >= 0) { izs[nz] = i0; kzs[nz] = 0; nz++; }
         izs[nz] = oz >> 1; kzs[nz] = 2; nz++; }
  if (oy & 1) { iys[0] = (oy - 1) >> 1; kys[0] = 1; ny = 1; }
  else { int i0 = (oy >> 1) - 1; if (i0 >= 0) { iys[ny] = i0; kys[ny] = 0; ny++; }
         iys[ny] = oy >> 1; kys[ny] = 2; ny++; }
  if (ox & 1) { ixs[0] = (ox - 1) >> 1; kxs[0] = 1; nx = 1; }
  else { int i0 = (ox >> 1) - 1; if (i0 >= 0) { ixs[nx] = i0; kxs[nx] = 0; nx++; }
         ixs[nx] = ox >> 1; kxs[nx] = 2; nx++; }

  int ci0 = blockIdx.y * ciPer, ci1 = ci0 + ciPer;
  long vin = (long)Din * Din * Din;
  float acc = 0.f;
  for (int ci = ci0; ci < ci1; ++ci) {
    const float* wp = w + ((long)co * Cin + ci) * 27;
    const float* ip = in + ci * vin;
    for (int a = 0; a < nz; a++)
      for (int b = 0; b < ny; b++)
        for (int c = 0; c < nx; c++)
          acc += ip[(izs[a] * Din + iys[b]) * Din + ixs[c]] *
                 wp[(kzs[a] * 3 + kys[b]) * 3 + kxs[c]];
  }
  outp[(long)blockIdx.y * total + idx] = acc;
}

// 1x1 fuse conv over concat(inA[C1], inB[C2])
__global__ __launch_bounds__(TPB) void k_fuse(const float* __restrict__ inA,
                                              const float* __restrict__ inB,
                                              const float* __restrict__ w,
                                              float* __restrict__ outp,
                                              int C1, int C2, int Cout, int vox,
                                              int ciPer) {
  long idx = blockIdx.x * (long)TPB + threadIdx.x;
  long total = (long)Cout * vox;
  if (idx >= total) return;
  int p = (int)(idx % vox);
  int co = (int)(idx / vox);
  int Cin = C1 + C2;
  int ci0 = blockIdx.y * ciPer, ci1 = ci0 + ciPer;
  float acc = 0.f;
  for (int ci = ci0; ci < ci1; ++ci) {
    float v = (ci < C1) ? inA[(long)ci * vox + p] : inB[(long)(ci - C1) * vox + p];
    acc += v * w[(long)co * Cin + ci];
  }
  outp[(long)blockIdx.y * total + idx] = acc;
}

__global__ __launch_bounds__(TPB) void k_sumparts(const float* __restrict__ parts,
                                                  float* __restrict__ out,
                                                  long n, int s) {
  long i = blockIdx.x * (long)TPB + threadIdx.x;
  if (i >= n) return;
  float a = 0.f;
  for (int j = 0; j < s; j++) a += parts[(long)j * n + i];
  out[i] = a;
}

// ================= masked BN =================
__global__ __launch_bounds__(TPB) void k_stats(const float* __restrict__ a,
                                               const float* __restrict__ m,
                                               float* __restrict__ stats, int vox) {
  int c = blockIdx.x;
  const float* ap = a + (long)c * vox;
  float s = 0.f, s2 = 0.f, sm = 0.f;
  for (int i = threadIdx.x; i < vox; i += TPB) {
    float mv = m[i];
    float v = ap[i] * mv;
    s += v; s2 += v * v; sm += mv;
  }
  __shared__ float sh0[TPB], sh1[TPB], sh2[TPB];
  sh0[threadIdx.x] = s; sh1[threadIdx.x] = s2; sh2[threadIdx.x] = sm;
  __syncthreads();
  for (int off = TPB / 2; off > 0; off >>= 1) {
    if (threadIdx.x < off) {
      sh0[threadIdx.x] += sh0[threadIdx.x + off];
      sh1[threadIdx.x] += sh1[threadIdx.x + off];
      sh2[threadIdx.x] += sh2[threadIdx.x + off];
    }
    __syncthreads();
  }
  if (threadIdx.x == 0) {
    float n = fmaxf(sh2[0], 1.f);
    float mu = sh0[0] / n;
    float var = fmaxf(sh1[0] / n - mu * mu, 0.f);
    stats[2 * c] = mu;
    stats[2 * c + 1] = rsqrtf(var + 1e-5f);
  }
}

__global__ __launch_bounds__(TPB) void k_apply(float* __restrict__ a,
                                               const float* __restrict__ m,
                                               const float* __restrict__ stats,
                                               int vox, long total) {
  long idx = blockIdx.x * (long)TPB + threadIdx.x;
  if (idx >= total) return;
  int c = (int)(idx / vox);
  int p = (int)(idx % vox);
  float v = (a[idx] - stats[2 * c]) * stats[2 * c + 1];
  a[idx] = fmaxf(v, 0.f) * m[p];
}

// final BN+ReLU+mask, FLOAT32 output (reference output dtype is f32!)
__global__ __launch_bounds__(TPB) void k_apply_out(const float* __restrict__ a,
                                                   const float* __restrict__ m,
                                                   const float* __restrict__ stats,
                                                   float* __restrict__ out,
                                                   int vox, long total) {
  long idx = blockIdx.x * (long)TPB + threadIdx.x;
  if (idx >= total) return;
  int c = (int)(idx / vox);
  int p = (int)(idx % vox);
  float v = (a[idx] - stats[2 * c]) * stats[2 * c + 1];
  out[idx] = fmaxf(v, 0.f) * m[p];
}

// ================= health diagnostics =================
__global__ __launch_bounds__(TPB) void k_health(const float* __restrict__ b, long n,
                                                int* __restrict__ hl, int k) {
  long i = blockIdx.x * (long)TPB + threadIdx.x;
  long stride = (long)gridDim.x * TPB;
  for (; i < n; i += stride)
    if (b[i] != 0.0f) { hl[k] = 1; return; }
}

__global__ void k_sentinel(const int* __restrict__ hl, int nst,
                           float* __restrict__ out) {
  if (threadIdx.x == 0 && blockIdx.x == 0) {
    for (int k = 0; k < nst; k++)
      if (hl[k] == 0) { out[0] = 64.0f * (k + 1); return; }
  }
}

// ================= workspace layout (floats) — masks FIRST =================
constexpr long o_m0 = 0;          // 64^3
constexpr long o_m1 = 262144;     // 32^3
constexpr long o_m2 = 294912;     // 16^3
constexpr long o_m3 = 299008;     // 8^3
constexpr long o_m4 = 299520;     // 4^3
constexpr long o_m5 = 299584;     // 2^3
constexpr long o_st = 299592;     // 2048 stats
constexpr long o_hl = 301640;     // 32 ints (health)
constexpr long o_A  = 301696;     // 2M: xm -> u3 -> (with B) final preact
constexpr long o_B  = 2398848;    // 2M: a0 (feats0)
constexpr long o_C  = 4496000;    // 512K: a1
constexpr long o_D  = 5020288;    // 128K: a2
constexpr long o_E  = 5151360;    // 32K: a3
constexpr long o_F  = 5184128;    // 8K: a4
constexpr long o_G  = 5192320;    // 8K: a5
constexpr long o_H  = 5200512;    // 32K: u0
constexpr long o_I  = 5233280;    // 32K: f0
constexpr long o_J  = 5266048;    // 128K: u1
constexpr long o_K  = 5397120;    // 128K: f1
constexpr long o_L  = 5528192;    // 512K: u2
constexpr long o_M  = 6052480;    // 512K: f2
constexpr long o_N  = 6576768;    // 2M: f3
constexpr long o_P  = 8673920;    // 512K: split-K partial scratch
constexpr long o_fin = o_A;       // 4M: final preact overlays A+B (both dead)
// total: 9198208 floats = 35.1 MB

extern "C" void kernel_launch(void* const* d_in, const int* in_sizes, int n_in,
                              void* d_out, int out_size, void* d_ws, size_t ws_size,
                              hipStream_t stream) {
  const float* x      = (const float*)d_in[0];
  const float* mask   = (const float*)d_in[1];
  const float* w_enc0 = (const float*)d_in[2];
  const float* w_enc1 = (const float*)d_in[3];
  const float* w_enc2 = (const float*)d_in[4];
  const float* w_enc3 = (const float*)d_in[5];
  const float* w_btd  = (const float*)d_in[6];
  const float* w_btc  = (const float*)d_in[7];
  const float* w_up0  = (const float*)d_in[8];
  const float* w_fu0  = (const float*)d_in[9];
  const float* w_up1  = (const float*)d_in[10];
  const float* w_fu1  = (const float*)d_in[11];
  const float* w_up2  = (const float*)d_in[12];
  const float* w_fu2  = (const float*)d_in[13];
  const float* w_up3  = (const float*)d_in[14];
  const float* w_fu3  = (const float*)d_in[15];
  const float* w_fin  = (const float*)d_in[16];

  float* ws = (float*)d_ws;
  float* st = ws + o_st;
  int* hl = (int*)(ws + o_hl);
  float* out = (float*)d_out;   // reference output dtype is float32

  auto blocks = [](long n) { return (unsigned)((n + TPB - 1) / TPB); };
  auto health = [&](const float* b, long n, int k) {
    long g = (n + TPB - 1) / TPB; if (g > 1024) g = 1024;
    k_health<<<(unsigned)g, TPB, 0, stream>>>(b, n, hl, k);
  };

  k_zero_int<<<1, TPB, 0, stream>>>(hl, 32);

  // masks
  k_mask0<<<blocks(262144), TPB, 0, stream>>>(mask, ws + o_m0, 262144);
  health(ws + o_m0, 262144, 0);
  k_downmask<<<blocks(32768), TPB, 0, stream>>>(ws + o_m0, ws + o_m1, 32);
  health(ws + o_m1, 32768, 1);
  k_downmask<<<blocks(4096), TPB, 0, stream>>>(ws + o_m1, ws + o_m2, 16);
  health(ws + o_m2, 4096, 2);
  k_downmask<<<blocks(512), TPB, 0, stream>>>(ws + o_m2, ws + o_m3, 8);
  health(ws + o_m3, 512, 3);
  k_downmask<<<blocks(64), TPB, 0, stream>>>(ws + o_m3, ws + o_m4, 4);
  health(ws + o_m4, 64, 4);
  k_downmask<<<blocks(8), TPB, 0, stream>>>(ws + o_m4, ws + o_m5, 2);
  health(ws + o_m5, 8, 5);

  // masked input -> A
  k_maskx<<<blocks(8L * 262144), TPB, 0, stream>>>(x, ws + o_m0, ws + o_A,
                                                   8L * 262144, 262144);
  health(ws + o_A, 8L * 262144, 6);

  auto conv = [&](const float* in, const float* w, float* o, int Cin, int Cout,
                  int Din, int Dout, int S, int P, int splits) {
    long total = (long)Cout * Dout * Dout * Dout;
    float* dst = (splits == 1) ? o : ws + o_P;
    dim3 g(blocks(total), splits);
    k_conv3<<<g, TPB, 0, stream>>>(in, w, dst, Cin, Cout, Din, Dout, S, P,
                                   Cin / splits);
    if (splits > 1)
      k_sumparts<<<blocks(total), TPB, 0, stream>>>(ws + o_P, o, total, splits);
  };
  auto convT = [&](const float* in, const float* w, float* o, int Cin, int Cout,
                   int Din, int splits) {
    int Dout = 2 * Din;
    long total = (long)Cout * Dout * Dout * Dout;
    float* dst = (splits == 1) ? o : ws + o_P;
    dim3 g(blocks(total), splits);
    k_convT<<<g, TPB, 0, stream>>>(in, w, dst, Cin, Cout, Din, Dout, Cin / splits);
    if (splits > 1)
      k_sumparts<<<blocks(total), TPB, 0, stream>>>(ws + o_P, o, total, splits);
  };
  auto fuse = [&](const float* a, const float* b, const float* w, float* o,
                  int C1, int C2, int Cout, int vox, int splits) {
    long total = (long)Cout * vox;
    float* dst = (splits == 1) ? o : ws + o_P;
    dim3 g(blocks(total), splits);
    k_fuse<<<g, TPB, 0, stream>>>(a, b, w, dst, C1, C2, Cout, vox,
                                  (C1 + C2) / splits);
    if (splits > 1)
      k_sumparts<<<blocks(total), TPB, 0, stream>>>(ws + o_P, o, total, splits);
  };
  auto bnrelu = [&](float* a, const float* m, int C, int vox) {
    k_stats<<<C, TPB, 0, stream>>>(a, m, st, vox);
    long total = (long)C * vox;
    k_apply<<<blocks(total), TPB, 0, stream>>>(a, m, st, vox, total);
  };

  // encoder
  conv(ws + o_A, w_enc0, ws + o_B, 8, 64, 64, 32, 2, 1, 1);
  bnrelu(ws + o_B, ws + o_m1, 64, 32768);           health(ws + o_B, 2097152, 7);
  conv(ws + o_B, w_enc1, ws + o_C, 64, 128, 32, 16, 2, 1, 1);
  bnrelu(ws + o_C, ws + o_m2, 128, 4096);           health(ws + o_C, 524288, 8);
  conv(ws + o_C, w_enc2, ws + o_D, 128, 256, 16, 8, 2, 1, 1);
  bnrelu(ws + o_D, ws + o_m3, 256, 512);            health(ws + o_D, 131072, 9);
  conv(ws + o_D, w_enc3, ws + o_E, 256, 512, 8, 4, 2, 1, 4);
  bnrelu(ws + o_E, ws + o_m4, 512, 64);             health(ws + o_E, 32768, 10);

  // bottleneck
  conv(ws + o_E, w_btd, ws + o_F, 512, 1024, 4, 2, 2, 1, 32);
  bnrelu(ws + o_F, ws + o_m5, 1024, 8);             health(ws + o_F, 8192, 11);
  conv(ws + o_F, w_btc, ws + o_G, 1024, 1024, 2, 2, 1, 1, 32);
  bnrelu(ws + o_G, ws + o_m5, 1024, 8);             health(ws + o_G, 8192, 12);

  // decoder
  convT(ws + o_G, w_up0, ws + o_H, 1024, 512, 2, 16);
  bnrelu(ws + o_H, ws + o_m4, 512, 64);             health(ws + o_H, 32768, 13);
  fuse(ws + o_H, ws + o_E, w_fu0, ws + o_I, 512, 512, 512, 64, 4);
  bnrelu(ws + o_I, ws + o_m4, 512, 64);             health(ws + o_I, 32768, 14);

  convT(ws + o_I, w_up1, ws + o_J, 512, 256, 4, 4);
  bnrelu(ws + o_J, ws + o_m3, 256, 512);            health(ws + o_J, 131072, 15);
  fuse(ws + o_J, ws + o_D, w_fu1, ws + o_K, 256, 256, 256, 512, 1);
  bnrelu(ws + o_K, ws + o_m3, 256, 512);            health(ws + o_K, 131072, 16);

  convT(ws + o_K, w_up2, ws + o_L, 256, 128, 8, 1);
  bnrelu(ws + o_L, ws + o_m2, 128, 4096);           health(ws + o_L, 524288, 17);
  fuse(ws + o_L, ws + o_C, w_fu2, ws + o_M, 128, 128, 128, 4096, 1);
  bnrelu(ws + o_M, ws + o_m2, 128, 4096);           health(ws + o_M, 524288, 18);

  convT(ws + o_M, w_up3, ws + o_A, 128, 64, 16, 1);
  bnrelu(ws + o_A, ws + o_m1, 64, 32768);           health(ws + o_A, 2097152, 19);
  fuse(ws + o_A, ws + o_B, w_fu3, ws + o_N, 64, 64, 64, 32768, 1);
  bnrelu(ws + o_N, ws + o_m1, 64, 32768);           health(ws + o_N, 2097152, 20);

  // final up to 64^3 (preact overlays A+B, both dead), BN over m0, write f32
  convT(ws + o_N, w_fin, ws + o_fin, 64, 16, 32, 1);
  health(ws + o_fin, 16L * 262144, 21);
  k_stats<<<16, TPB, 0, stream>>>(ws + o_fin, ws + o_m0, st, 262144);
  long total = 16L * 262144;
  k_apply_out<<<blocks(total), TPB, 0, stream>>>(ws + o_fin, ws + o_m0, st, out,
                                                 262144, total);
  // diagnostic: if any stage was all-zero, stamp 64*(stage+1) into out[0]
  k_sentinel<<<1, 64, 0, stream>>>(hl, 22, out);
}

// Round 5
// 5146.442 us; speedup vs baseline: 1.0921x; 1.0921x over previous
//
#include <hip/hip_runtime.h>
#include <hip/hip_bf16.h>

#define TPB 256

// ================= masks =================
__global__ __launch_bounds__(TPB) void k_mask0(const float* __restrict__ mask,
                                               float* __restrict__ m0, int n) {
  int i = blockIdx.x * TPB + threadIdx.x;
  if (i < n) m0[i] = (mask[i] < 0.1f) ? 1.0f : 0.0f;
}

__global__ __launch_bounds__(TPB) void k_downmask(const float* __restrict__ mi,
                                                  float* __restrict__ mo, int Dout) {
  int n = Dout * Dout * Dout;
  int idx = blockIdx.x * TPB + threadIdx.x;
  if (idx >= n) return;
  int Din = Dout * 2;
  int ox = idx % Dout, oy = (idx / Dout) % Dout, oz = idx / (Dout * Dout);
  float v = 0.f;
  for (int kz = 0; kz < 3; kz++) {
    int iz = 2 * oz + kz - 1; if ((unsigned)iz >= (unsigned)Din) continue;
    for (int ky = 0; ky < 3; ky++) {
      int iy = 2 * oy + ky - 1; if ((unsigned)iy >= (unsigned)Din) continue;
      for (int kx = 0; kx < 3; kx++) {
        int ix = 2 * ox + kx - 1; if ((unsigned)ix >= (unsigned)Din) continue;
        v = fmaxf(v, mi[(iz * Din + iy) * Din + ix]);
      }
    }
  }
  mo[idx] = v;
}

__global__ __launch_bounds__(TPB) void k_maskx(const float* __restrict__ x,
                                               const float* __restrict__ m,
                                               float* __restrict__ o,
                                               long total, int vox) {
  long i = blockIdx.x * (long)TPB + threadIdx.x;
  if (i < total) o[i] = x[i] * m[i % vox];
}

// ================= legacy scalar convs (tiny-N layers only) =================
__global__ __launch_bounds__(TPB) void k_conv3(const float* __restrict__ in,
                                               const float* __restrict__ w,
                                               float* __restrict__ outp,
                                               int Cin, int Cout, int Din, int Dout,
                                               int S, int P, int ciPer) {
  long idx = blockIdx.x * (long)TPB + threadIdx.x;
  int vox = Dout * Dout * Dout;
  long total = (long)Cout * vox;
  if (idx >= total) return;
  int p = (int)(idx % vox);
  int co = (int)(idx / vox);
  int ox = p % Dout, oy = (p / Dout) % Dout, oz = p / (Dout * Dout);
  int ci0 = blockIdx.y * ciPer, ci1 = ci0 + ciPer;
  float acc = 0.f;
  for (int ci = ci0; ci < ci1; ++ci) {
    const float* wp = w + ((long)co * Cin + ci) * 27;
    const float* ip = in + (long)ci * Din * Din * Din;
    for (int kz = 0; kz < 3; kz++) {
      int iz = S * oz + kz - P; if ((unsigned)iz >= (unsigned)Din) continue;
      for (int ky = 0; ky < 3; ky++) {
        int iy = S * oy + ky - P; if ((unsigned)iy >= (unsigned)Din) continue;
        for (int kx = 0; kx < 3; kx++) {
          int ix = S * ox + kx - P; if ((unsigned)ix >= (unsigned)Din) continue;
          acc += ip[(iz * Din + iy) * Din + ix] * wp[(kz * 3 + ky) * 3 + kx];
        }
      }
    }
  }
  outp[(long)blockIdx.y * total + idx] = acc;
}

__global__ __launch_bounds__(TPB) void k_convT(const float* __restrict__ in,
                                               const float* __restrict__ w,
                                               float* __restrict__ outp,
                                               int Cin, int Cout, int Din, int Dout,
                                               int ciPer) {
  long idx = blockIdx.x * (long)TPB + threadIdx.x;
  int vox = Dout * Dout * Dout;
  long total = (long)Cout * vox;
  if (idx >= total) return;
  int p = (int)(idx % vox);
  int co = (int)(idx / vox);
  int ox = p % Dout, oy = (p / Dout) % Dout, oz = p / (Dout * Dout);

  int izs[2], kzs[2], nz = 0;
  int iys[2], kys[2], ny = 0;
  int ixs[2], kxs[2], nx = 0;
  if (oz & 1) { izs[0] = (oz - 1) >> 1; kzs[0] = 1; nz = 1; }
  else { int i0 = (oz >> 1) - 1; if (i0 >= 0) { izs[nz] = i0; kzs[nz] = 0; nz++; }
         izs[nz] = oz >> 1; kzs[nz] = 2; nz++; }
  if (oy & 1) { iys[0] = (oy - 1) >> 1; kys[0] = 1; ny = 1; }
  else { int i0 = (oy >> 1) - 1; if (i0 >= 0) { iys[ny] = i0; kys[ny] = 0; ny++; }
         iys[ny] = oy >> 1; kys[ny] = 2; ny++; }
  if (ox & 1) { ixs[0] = (ox - 1) >> 1; kxs[0] = 1; nx = 1; }
  else { int i0 = (ox >> 1) - 1; if (i0 >= 0) { ixs[nx] = i0; kxs[nx] = 0; nx++; }
         ixs[nx] = ox >> 1; kxs[nx] = 2; nx++; }

  int ci0 = blockIdx.y * ciPer, ci1 = ci0 + ciPer;
  long vin = (long)Din * Din * Din;
  float acc = 0.f;
  for (int ci = ci0; ci < ci1; ++ci) {
    const float* wp = w + ((long)co * Cin + ci) * 27;
    const float* ip = in + ci * vin;
    for (int a = 0; a < nz; a++)
      for (int b = 0; b < ny; b++)
        for (int c = 0; c < nx; c++)
          acc += ip[(izs[a] * Din + iys[b]) * Din + ixs[c]] *
                 wp[(kzs[a] * 3 + kys[b]) * 3 + kxs[c]];
  }
  outp[(long)blockIdx.y * total + idx] = acc;
}

__global__ __launch_bounds__(TPB) void k_fuse(const float* __restrict__ inA,
                                              const float* __restrict__ inB,
                                              const float* __restrict__ w,
                                              float* __restrict__ outp,
                                              int C1, int C2, int Cout, int vox,
                                              int ciPer) {
  long idx = blockIdx.x * (long)TPB + threadIdx.x;
  long total = (long)Cout * vox;
  if (idx >= total) return;
  int p = (int)(idx % vox);
  int co = (int)(idx / vox);
  int Cin = C1 + C2;
  int ci0 = blockIdx.y * ciPer, ci1 = ci0 + ciPer;
  float acc = 0.f;
  for (int ci = ci0; ci < ci1; ++ci) {
    float v = (ci < C1) ? inA[(long)ci * vox + p] : inB[(long)(ci - C1) * vox + p];
    acc += v * w[(long)co * Cin + ci];
  }
  outp[(long)blockIdx.y * total + idx] = acc;
}

__global__ __launch_bounds__(TPB) void k_sumparts(const float* __restrict__ parts,
                                                  float* __restrict__ out,
                                                  long n, int s) {
  long i = blockIdx.x * (long)TPB + threadIdx.x;
  if (i >= n) return;
  float a = 0.f;
  for (int j = 0; j < s; j++) a += parts[(long)j * n + i];
  out[i] = a;
}

// ================= tiled implicit-GEMM =================
// C[M][N] = A[M][K] x B[K][N]
// MODE 0: conv k3 s2 p1   (k -> ci,kz,ky,kx; i = 2o + k - 1)
// MODE 1: convT k3 s2 SAME (valid iff (o+k) even per dim; i = (o+k)/2 - 1)
// MODE 2: 1x1 fuse over concat(B1[C1], B2[K-C1])
// Tiles: MT x 64 x 32. Block 256 threads, micro-tile (MT/16) x 4.
template<int MT, int MODE>
__global__ __launch_bounds__(TPB) void k_gemm(const float* __restrict__ A,
                                              const float* __restrict__ B1,
                                              const float* __restrict__ B2,
                                              float* __restrict__ C,
                                              int M, int N, int K,
                                              int Din, int Dout, int C1) {
  constexpr int MR = MT / 16;
  __shared__ __align__(16) float At[32][MT];
  __shared__ __align__(16) float Bt[32][64];

  const int t = threadIdx.x;
  const int n0 = blockIdx.x * 64;
  const int m0 = blockIdx.y * MT;

  const int tx = t & 15;          // p-quad
  const int tyf = t >> 4;         // co group (0..15)
  const int p0 = tx * 4;
  const int co0 = tyf * MR;

  const int pb = t & 63;
  const int kb0 = (t >> 6) * 8;
  const int pp = n0 + pb;
  const int oxb = pp & (Dout - 1);
  const int oyb = (pp / Dout) & (Dout - 1);
  const int ozb = pp / (Dout * Dout);

  float acc[MR][4];
#pragma unroll
  for (int a = 0; a < MR; a++)
#pragma unroll
    for (int b = 0; b < 4; b++) acc[a][b] = 0.f;

  const int nch = (K + 31) >> 5;
  for (int c = 0; c < nch; ++c) {
    const int k0 = c << 5;
    __syncthreads();
    // ---- stage A (transposed: At[k][co] = A[co][k]) ----
    if (MT == 64) {
      const int co_a = t >> 2;
      const int ka = (t & 3) * 8;
#pragma unroll
      for (int j = 0; j < 2; j++) {
        const int kg = k0 + ka + j * 4;
        float4 v = make_float4(0.f, 0.f, 0.f, 0.f);
        if (kg < K) v = *(const float4*)&A[(long)(m0 + co_a) * K + kg];
        At[ka + j * 4 + 0][co_a] = v.x;
        At[ka + j * 4 + 1][co_a] = v.y;
        At[ka + j * 4 + 2][co_a] = v.z;
        At[ka + j * 4 + 3][co_a] = v.w;
      }
    } else { // MT == 16
      const int co_a = t >> 4;
      const int ka = (t & 15) * 2;
#pragma unroll
      for (int j = 0; j < 2; j++) {
        const int kg = k0 + ka + j;
        At[ka + j][co_a] = (kg < K) ? A[(long)(m0 + co_a) * K + kg] : 0.f;
      }
    }
    // ---- stage B (implicit im2col gather) ----
#pragma unroll
    for (int j = 0; j < 8; j++) {
      const int kb = kb0 + j;
      const int kg = k0 + kb;
      float v = 0.f;
      if (kg < K) {
        if (MODE == 2) {
          v = (kg < C1) ? B1[(long)kg * N + pp] : B2[(long)(kg - C1) * N + pp];
        } else {
          const int ci = kg / 27;
          const int tap = kg - ci * 27;
          const int kz = tap / 9;
          const int r9 = tap - kz * 9;
          const int ky = r9 / 3;
          const int kx = r9 - ky * 3;
          int iz, iy, ix;
          bool ok;
          if (MODE == 0) {
            iz = 2 * ozb + kz - 1; iy = 2 * oyb + ky - 1; ix = 2 * oxb + kx - 1;
            ok = (unsigned)iz < (unsigned)Din && (unsigned)iy < (unsigned)Din &&
                 (unsigned)ix < (unsigned)Din;
          } else {
            const int z2 = ozb + kz, y2 = oyb + ky, x2 = oxb + kx;
            iz = (z2 >> 1) - 1; iy = (y2 >> 1) - 1; ix = (x2 >> 1) - 1;
            ok = !((z2 | y2 | x2) & 1) &&
                 (unsigned)iz < (unsigned)Din && (unsigned)iy < (unsigned)Din &&
                 (unsigned)ix < (unsigned)Din;
          }
          if (ok)
            v = B1[(long)ci * Din * Din * Din + (iz * Din + iy) * Din + ix];
        }
      }
      Bt[kb][pb] = v;
    }
    __syncthreads();
    // ---- compute ----
#pragma unroll
    for (int kk = 0; kk < 32; ++kk) {
      const float4 b4 = *(const float4*)&Bt[kk][p0];
      if (MR == 4) {
        const float4 a4 = *(const float4*)&At[kk][co0];
        acc[0][0] += a4.x * b4.x; acc[0][1] += a4.x * b4.y;
        acc[0][2] += a4.x * b4.z; acc[0][3] += a4.x * b4.w;
        acc[1][0] += a4.y * b4.x; acc[1][1] += a4.y * b4.y;
        acc[1][2] += a4.y * b4.z; acc[1][3] += a4.y * b4.w;
        acc[2][0] += a4.z * b4.x; acc[2][1] += a4.z * b4.y;
        acc[2][2] += a4.z * b4.z; acc[2][3] += a4.z * b4.w;
        acc[3][0] += a4.w * b4.x; acc[3][1] += a4.w * b4.y;
        acc[3][2] += a4.w * b4.z; acc[3][3] += a4.w * b4.w;
      } else {
        const float a = At[kk][co0];
        acc[0][0] += a * b4.x; acc[0][1] += a * b4.y;
        acc[0][2] += a * b4.z; acc[0][3] += a * b4.w;
      }
    }
  }
  // ---- epilogue ----
#pragma unroll
  for (int mr = 0; mr < MR; mr++) {
    float4 v = make_float4(acc[mr][0], acc[mr][1], acc[mr][2], acc[mr][3]);
    *(float4*)&C[(long)(m0 + co0 + mr) * N + n0 + p0] = v;
  }
}

// ================= masked BN =================
__global__ __launch_bounds__(TPB) void k_stats(const float* __restrict__ a,
                                               const float* __restrict__ m,
                                               float* __restrict__ stats, int vox) {
  int c = blockIdx.x;
  const float* ap = a + (long)c * vox;
  float s = 0.f, s2 = 0.f, sm = 0.f;
  for (int i = threadIdx.x; i < vox; i += TPB) {
    float mv = m[i];
    float v = ap[i] * mv;
    s += v; s2 += v * v; sm += mv;
  }
  __shared__ float sh0[TPB], sh1[TPB], sh2[TPB];
  sh0[threadIdx.x] = s; sh1[threadIdx.x] = s2; sh2[threadIdx.x] = sm;
  __syncthreads();
  for (int off = TPB / 2; off > 0; off >>= 1) {
    if (threadIdx.x < off) {
      sh0[threadIdx.x] += sh0[threadIdx.x + off];
      sh1[threadIdx.x] += sh1[threadIdx.x + off];
      sh2[threadIdx.x] += sh2[threadIdx.x + off];
    }
    __syncthreads();
  }
  if (threadIdx.x == 0) {
    float n = fmaxf(sh2[0], 1.f);
    float mu = sh0[0] / n;
    float var = fmaxf(sh1[0] / n - mu * mu, 0.f);
    stats[2 * c] = mu;
    stats[2 * c + 1] = rsqrtf(var + 1e-5f);
  }
}

__global__ __launch_bounds__(TPB) void k_apply(float* __restrict__ a,
                                               const float* __restrict__ m,
                                               const float* __restrict__ stats,
                                               int vox, long total) {
  long idx = blockIdx.x * (long)TPB + threadIdx.x;
  if (idx >= total) return;
  int c = (int)(idx / vox);
  int p = (int)(idx % vox);
  float v = (a[idx] - stats[2 * c]) * stats[2 * c + 1];
  a[idx] = fmaxf(v, 0.f) * m[p];
}

__global__ __launch_bounds__(TPB) void k_apply_out(const float* __restrict__ a,
                                                   const float* __restrict__ m,
                                                   const float* __restrict__ stats,
                                                   float* __restrict__ out,
                                                   int vox, long total) {
  long idx = blockIdx.x * (long)TPB + threadIdx.x;
  if (idx >= total) return;
  int c = (int)(idx / vox);
  int p = (int)(idx % vox);
  float v = (a[idx] - stats[2 * c]) * stats[2 * c + 1];
  out[idx] = fmaxf(v, 0.f) * m[p];
}

// ================= workspace layout (floats) =================
constexpr long o_m0 = 0;          // 64^3
constexpr long o_m1 = 262144;     // 32^3
constexpr long o_m2 = 294912;     // 16^3
constexpr long o_m3 = 299008;     // 8^3
constexpr long o_m4 = 299520;     // 4^3
constexpr long o_m5 = 299584;     // 2^3
constexpr long o_st = 299592;     // 2048 stats
constexpr long o_A  = 301696;     // 2M: xm -> u3 -> (with B) final preact
constexpr long o_B  = 2398848;    // 2M: a0 (feats0)
constexpr long o_C  = 4496000;    // 512K: a1 (feats1)
constexpr long o_D  = 5020288;    // 128K: a2 (feats2)
constexpr long o_E  = 5151360;    // 32K: a3 (feats3)
constexpr long o_F  = 5184128;    // 8K: a4
constexpr long o_G  = 5192320;    // 8K: a5
constexpr long o_H  = 5200512;    // 32K: u0
constexpr long o_I  = 5233280;    // 32K: f0
constexpr long o_J  = 5266048;    // 128K: u1
constexpr long o_K  = 5397120;    // 128K: f1
constexpr long o_L  = 5528192;    // 512K: u2
constexpr long o_M  = 6052480;    // 512K: f2
constexpr long o_N  = 6576768;    // 2M: f3
constexpr long o_P  = 8673920;    // 512K: split-K partial scratch
constexpr long o_fin = o_A;       // 4M: final preact overlays A+B

extern "C" void kernel_launch(void* const* d_in, const int* in_sizes, int n_in,
                              void* d_out, int out_size, void* d_ws, size_t ws_size,
                              hipStream_t stream) {
  const float* x      = (const float*)d_in[0];
  const float* mask   = (const float*)d_in[1];
  const float* w_enc0 = (const float*)d_in[2];
  const float* w_enc1 = (const float*)d_in[3];
  const float* w_enc2 = (const float*)d_in[4];
  const float* w_enc3 = (const float*)d_in[5];
  const float* w_btd  = (const float*)d_in[6];
  const float* w_btc  = (const float*)d_in[7];
  const float* w_up0  = (const float*)d_in[8];
  const float* w_fu0  = (const float*)d_in[9];
  const float* w_up1  = (const float*)d_in[10];
  const float* w_fu1  = (const float*)d_in[11];
  const float* w_up2  = (const float*)d_in[12];
  const float* w_fu2  = (const float*)d_in[13];
  const float* w_up3  = (const float*)d_in[14];
  const float* w_fu3  = (const float*)d_in[15];
  const float* w_fin  = (const float*)d_in[16];

  float* ws = (float*)d_ws;
  float* st = ws + o_st;
  float* out = (float*)d_out;

  auto blocks = [](long n) { return (unsigned)((n + TPB - 1) / TPB); };

  // masks
  k_mask0<<<blocks(262144), TPB, 0, stream>>>(mask, ws + o_m0, 262144);
  k_downmask<<<blocks(32768), TPB, 0, stream>>>(ws + o_m0, ws + o_m1, 32);
  k_downmask<<<blocks(4096), TPB, 0, stream>>>(ws + o_m1, ws + o_m2, 16);
  k_downmask<<<blocks(512), TPB, 0, stream>>>(ws + o_m2, ws + o_m3, 8);
  k_downmask<<<blocks(64), TPB, 0, stream>>>(ws + o_m3, ws + o_m4, 4);
  k_downmask<<<blocks(8), TPB, 0, stream>>>(ws + o_m4, ws + o_m5, 2);

  // masked input -> A
  k_maskx<<<blocks(8L * 262144), TPB, 0, stream>>>(x, ws + o_m0, ws + o_A,
                                                   8L * 262144, 262144);

  // legacy dispatch helpers (tiny-N layers)
  auto conv = [&](const float* in, const float* w, float* o, int Cin, int Cout,
                  int Din, int Dout, int S, int P, int splits) {
    long total = (long)Cout * Dout * Dout * Dout;
    float* dst = (splits == 1) ? o : ws + o_P;
    dim3 g(blocks(total), splits);
    k_conv3<<<g, TPB, 0, stream>>>(in, w, dst, Cin, Cout, Din, Dout, S, P,
                                   Cin / splits);
    if (splits > 1)
      k_sumparts<<<blocks(total), TPB, 0, stream>>>(ws + o_P, o, total, splits);
  };
  auto convT = [&](const float* in, const float* w, float* o, int Cin, int Cout,
                   int Din, int splits) {
    int Dout = 2 * Din;
    long total = (long)Cout * Dout * Dout * Dout;
    float* dst = (splits == 1) ? o : ws + o_P;
    dim3 g(blocks(total), splits);
    k_convT<<<g, TPB, 0, stream>>>(in, w, dst, Cin, Cout, Din, Dout, Cin / splits);
    if (splits > 1)
      k_sumparts<<<blocks(total), TPB, 0, stream>>>(ws + o_P, o, total, splits);
  };
  auto fuseOld = [&](const float* a, const float* b, const float* w, float* o,
                     int C1, int C2, int Cout, int vox, int splits) {
    long total = (long)Cout * vox;
    float* dst = (splits == 1) ? o : ws + o_P;
    dim3 g(blocks(total), splits);
    k_fuse<<<g, TPB, 0, stream>>>(a, b, w, dst, C1, C2, Cout, vox,
                                  (C1 + C2) / splits);
    if (splits > 1)
      k_sumparts<<<blocks(total), TPB, 0, stream>>>(ws + o_P, o, total, splits);
  };
  auto bnrelu = [&](float* a, const float* m, int C, int vox) {
    k_stats<<<C, TPB, 0, stream>>>(a, m, st, vox);
    long total = (long)C * vox;
    k_apply<<<blocks(total), TPB, 0, stream>>>(a, m, st, vox, total);
  };

  // tiled-GEMM dispatch helpers
  auto gconv = [&](const float* w, const float* in, float* o, int M, int N, int K,
                   int Din, int Dout) {
    dim3 g(N / 64, M / 64);
    k_gemm<64, 0><<<g, TPB, 0, stream>>>(w, in, nullptr, o, M, N, K, Din, Dout, 0);
  };
  auto gconvT = [&](const float* w, const float* in, float* o, int M, int N, int K,
                    int Din, int Dout) {
    dim3 g(N / 64, M / 64);
    k_gemm<64, 1><<<g, TPB, 0, stream>>>(w, in, nullptr, o, M, N, K, Din, Dout, 0);
  };
  auto gfuse = [&](const float* w, const float* a, const float* b, float* o,
                   int M, int N, int C1, int C2) {
    dim3 g(N / 64, M / 64);
    k_gemm<64, 2><<<g, TPB, 0, stream>>>(w, a, b, o, M, N, C1 + C2, 0, 0, C1);
  };

  // ---------------- encoder ----------------
  gconv(w_enc0, ws + o_A, ws + o_B, 64, 32768, 8 * 27, 64, 32);
  bnrelu(ws + o_B, ws + o_m1, 64, 32768);
  gconv(w_enc1, ws + o_B, ws + o_C, 128, 4096, 64 * 27, 32, 16);
  bnrelu(ws + o_C, ws + o_m2, 128, 4096);
  gconv(w_enc2, ws + o_C, ws + o_D, 256, 512, 128 * 27, 16, 8);
  bnrelu(ws + o_D, ws + o_m3, 256, 512);
  conv(ws + o_D, w_enc3, ws + o_E, 256, 512, 8, 4, 2, 1, 4);
  bnrelu(ws + o_E, ws + o_m4, 512, 64);

  // ---------------- bottleneck ----------------
  conv(ws + o_E, w_btd, ws + o_F, 512, 1024, 4, 2, 2, 1, 32);
  bnrelu(ws + o_F, ws + o_m5, 1024, 8);
  conv(ws + o_F, w_btc, ws + o_G, 1024, 1024, 2, 2, 1, 1, 32);
  bnrelu(ws + o_G, ws + o_m5, 1024, 8);

  // ---------------- decoder ----------------
  convT(ws + o_G, w_up0, ws + o_H, 1024, 512, 2, 16);
  bnrelu(ws + o_H, ws + o_m4, 512, 64);
  fuseOld(ws + o_H, ws + o_E, w_fu0, ws + o_I, 512, 512, 512, 64, 4);
  bnrelu(ws + o_I, ws + o_m4, 512, 64);

  gconvT(w_up1, ws + o_I, ws + o_J, 256, 512, 512 * 27, 4, 8);
  bnrelu(ws + o_J, ws + o_m3, 256, 512);
  gfuse(w_fu1, ws + o_J, ws + o_D, ws + o_K, 256, 512, 256, 256);
  bnrelu(ws + o_K, ws + o_m3, 256, 512);

  gconvT(w_up2, ws + o_K, ws + o_L, 128, 4096, 256 * 27, 8, 16);
  bnrelu(ws + o_L, ws + o_m2, 128, 4096);
  gfuse(w_fu2, ws + o_L, ws + o_C, ws + o_M, 128, 4096, 128, 128);  // skip = a1 (o_C)!
  bnrelu(ws + o_M, ws + o_m2, 128, 4096);

  gconvT(w_up3, ws + o_M, ws + o_A, 64, 32768, 128 * 27, 16, 32);
  bnrelu(ws + o_A, ws + o_m1, 64, 32768);
  gfuse(w_fu3, ws + o_A, ws + o_B, ws + o_N, 64, 32768, 64, 64);   // skip = a0 (o_B)
  bnrelu(ws + o_N, ws + o_m1, 64, 32768);

  // ---------------- final up ----------------
  {
    dim3 g(262144 / 64, 1);
    k_gemm<16, 1><<<g, TPB, 0, stream>>>(w_fin, ws + o_N, nullptr, ws + o_fin,
                                         16, 262144, 64 * 27, 32, 64, 0);
  }
  k_stats<<<16, TPB, 0, stream>>>(ws + o_fin, ws + o_m0, st, 262144);
  long total = 16L * 262144;
  k_apply_out<<<blocks(total), TPB, 0, stream>>>(ws + o_fin, ws + o_m0, st, out,
                                                 262144, total);
}

// Round 6
// 2374.401 us; speedup vs baseline: 2.3670x; 2.1675x over previous
//
#include <hip/hip_runtime.h>
#include <hip/hip_bf16.h>

#define TPB 256

// ================= masks =================
__global__ __launch_bounds__(TPB) void k_mask0(const float* __restrict__ mask,
                                               float* __restrict__ m0, int n) {
  int i = blockIdx.x * TPB + threadIdx.x;
  if (i < n) m0[i] = (mask[i] < 0.1f) ? 1.0f : 0.0f;
}

__global__ __launch_bounds__(TPB) void k_downmask(const float* __restrict__ mi,
                                                  float* __restrict__ mo, int Dout) {
  int n = Dout * Dout * Dout;
  int idx = blockIdx.x * TPB + threadIdx.x;
  if (idx >= n) return;
  int Din = Dout * 2;
  int ox = idx % Dout, oy = (idx / Dout) % Dout, oz = idx / (Dout * Dout);
  float v = 0.f;
  for (int kz = 0; kz < 3; kz++) {
    int iz = 2 * oz + kz - 1; if ((unsigned)iz >= (unsigned)Din) continue;
    for (int ky = 0; ky < 3; ky++) {
      int iy = 2 * oy + ky - 1; if ((unsigned)iy >= (unsigned)Din) continue;
      for (int kx = 0; kx < 3; kx++) {
        int ix = 2 * ox + kx - 1; if ((unsigned)ix >= (unsigned)Din) continue;
        v = fmaxf(v, mi[(iz * Din + iy) * Din + ix]);
      }
    }
  }
  mo[idx] = v;
}

__global__ __launch_bounds__(TPB) void k_maskx(const float* __restrict__ x,
                                               const float* __restrict__ m,
                                               float* __restrict__ o,
                                               long total, int vox) {
  long i = blockIdx.x * (long)TPB + threadIdx.x;
  if (i < total) o[i] = x[i] * m[i % vox];
}

__global__ __launch_bounds__(TPB) void k_sumparts(const float* __restrict__ parts,
                                                  float* __restrict__ out,
                                                  long n, int s) {
  long i = blockIdx.x * (long)TPB + threadIdx.x;
  if (i >= n) return;
  float a = 0.f;
  for (int j = 0; j < s; j++) a += parts[(long)j * n + i];
  out[i] = a;
}

// ================= tiled implicit-GEMM, split-K, reg-prefetch =================
// C[M][N] = A[M][K] x B[K][N];  k = (ci, kz, ky, kx) with 27 taps (modes 0/1/3)
// MODE 0: conv k3 s2 p1    (i = 2o + k - 1)
// MODE 1: convT k3 s2 SAME (valid iff (o+k) even per dim; i = (o+k)/2 - 1)
// MODE 2: 1x1 fuse over concat(B1[C1], B2[K-C1])
// MODE 3: conv k3 s1 p1    (i = o + k - 1)
// Tile MT x 64 x 32; 256 threads; micro-tile (MT/16) x 4.
// Split-K: blockIdx.z handles kcPer K-chunks, writes C + z*M*N (partials).
template<int MT, int MODE>
__global__ __launch_bounds__(TPB) void k_gemm(const float* __restrict__ A,
                                              const float* __restrict__ B1,
                                              const float* __restrict__ B2,
                                              float* __restrict__ C,
                                              int M, int N, int K,
                                              int Din, int Dout, int C1,
                                              int kcPer) {
  constexpr int MR = MT / 16;
  __shared__ __align__(16) float At[32][MT];
  __shared__ __align__(16) float Bt[32][64];

  const int t = threadIdx.x;
  const int n0 = blockIdx.x * 64;
  const int m0 = blockIdx.y * MT;

  const int tx = t & 15;
  const int p0 = tx * 4;
  const int co0 = (t >> 4) * MR;

  const int pb = t & 63;
  const int kb0 = (t >> 6) * 8;
  const int pp = n0 + pb;
  const int oxb = pp & (Dout - 1);
  const int oyb = (pp / Dout) & (Dout - 1);
  const int ozb = pp / (Dout * Dout);

  const int nch = (K + 31) >> 5;
  const int c0 = blockIdx.z * kcPer;
  int c1 = c0 + kcPer; if (c1 > nch) c1 = nch;

  float acc[MR][4];
#pragma unroll
  for (int a = 0; a < MR; a++)
#pragma unroll
    for (int b = 0; b < 4; b++) acc[a][b] = 0.f;

  // prefetch registers
  float4 ra[2];
  float rb[8];
  const int co_a = (MT == 64) ? (t >> 2) : (t >> 4);
  const int ka   = (MT == 64) ? ((t & 3) * 8) : ((t & 15) * 2);
  const long arow = (long)(m0 + co_a) * K;

  auto loadA = [&](int c) {
    const int k0 = c << 5;
    if (MT == 64) {
#pragma unroll
      for (int j = 0; j < 2; j++) {
        const int kg = k0 + ka + j * 4;
        ra[j] = (kg < K) ? *(const float4*)&A[arow + kg]
                         : make_float4(0.f, 0.f, 0.f, 0.f);
      }
    } else {
      const int kg = k0 + ka;
      ra[0].x = (kg < K) ? A[arow + kg] : 0.f;
      ra[0].y = (kg + 1 < K) ? A[arow + kg + 1] : 0.f;
    }
  };
  auto loadB = [&](int c) {
    const int k0 = c << 5;
#pragma unroll
    for (int j = 0; j < 8; j++) {
      const int kg = k0 + kb0 + j;
      float v = 0.f;
      if (kg < K && pp < N) {
        if (MODE == 2) {
          v = (kg < C1) ? B1[(long)kg * N + pp] : B2[(long)(kg - C1) * N + pp];
        } else {
          const int ci = kg / 27;
          const int tap = kg - ci * 27;
          const int kz = tap / 9;
          const int r9 = tap - kz * 9;
          const int ky = r9 / 3;
          const int kx = r9 - ky * 3;
          int iz, iy, ix;
          bool ok;
          if (MODE == 0) {
            iz = 2 * ozb + kz - 1; iy = 2 * oyb + ky - 1; ix = 2 * oxb + kx - 1;
            ok = (unsigned)iz < (unsigned)Din && (unsigned)iy < (unsigned)Din &&
                 (unsigned)ix < (unsigned)Din;
          } else if (MODE == 3) {
            iz = ozb + kz - 1; iy = oyb + ky - 1; ix = oxb + kx - 1;
            ok = (unsigned)iz < (unsigned)Din && (unsigned)iy < (unsigned)Din &&
                 (unsigned)ix < (unsigned)Din;
          } else { // MODE 1
            const int z2 = ozb + kz, y2 = oyb + ky, x2 = oxb + kx;
            iz = (z2 >> 1) - 1; iy = (y2 >> 1) - 1; ix = (x2 >> 1) - 1;
            ok = !((z2 | y2 | x2) & 1) &&
                 (unsigned)iz < (unsigned)Din && (unsigned)iy < (unsigned)Din &&
                 (unsigned)ix < (unsigned)Din;
          }
          if (ok)
            v = B1[(long)ci * Din * Din * Din + (iz * Din + iy) * Din + ix];
        }
      }
      rb[j] = v;
    }
  };

  if (c0 < c1) { loadA(c0); loadB(c0); }

  for (int c = c0; c < c1; ++c) {
    __syncthreads();  // previous compute done reading LDS
    // regs -> LDS
    if (MT == 64) {
#pragma unroll
      for (int j = 0; j < 2; j++) {
        At[ka + j * 4 + 0][co_a] = ra[j].x;
        At[ka + j * 4 + 1][co_a] = ra[j].y;
        At[ka + j * 4 + 2][co_a] = ra[j].z;
        At[ka + j * 4 + 3][co_a] = ra[j].w;
      }
    } else {
      At[ka][co_a] = ra[0].x;
      At[ka + 1][co_a] = ra[0].y;
    }
#pragma unroll
    for (int j = 0; j < 8; j++) Bt[kb0 + j][pb] = rb[j];
    // issue next chunk's global loads; latency hides under compute below
    if (c + 1 < c1) { loadA(c + 1); loadB(c + 1); }
    __syncthreads();
    // compute
#pragma unroll
    for (int kk = 0; kk < 32; ++kk) {
      const float4 b4 = *(const float4*)&Bt[kk][p0];
      if (MR == 4) {
        const float4 a4 = *(const float4*)&At[kk][co0];
        acc[0][0] += a4.x * b4.x; acc[0][1] += a4.x * b4.y;
        acc[0][2] += a4.x * b4.z; acc[0][3] += a4.x * b4.w;
        acc[1][0] += a4.y * b4.x; acc[1][1] += a4.y * b4.y;
        acc[1][2] += a4.y * b4.z; acc[1][3] += a4.y * b4.w;
        acc[2][0] += a4.z * b4.x; acc[2][1] += a4.z * b4.y;
        acc[2][2] += a4.z * b4.z; acc[2][3] += a4.z * b4.w;
        acc[3][0] += a4.w * b4.x; acc[3][1] += a4.w * b4.y;
        acc[3][2] += a4.w * b4.z; acc[3][3] += a4.w * b4.w;
      } else {
        const float a = At[kk][co0];
        acc[0][0] += a * b4.x; acc[0][1] += a * b4.y;
        acc[0][2] += a * b4.z; acc[0][3] += a * b4.w;
      }
    }
  }
  // epilogue: write (partial) tile; z-slice offset for split-K
  float* Cz = C + (long)blockIdx.z * ((long)M * N);
#pragma unroll
  for (int mr = 0; mr < MR; mr++) {
    if (n0 + p0 < N) {
      float4 v = make_float4(acc[mr][0], acc[mr][1], acc[mr][2], acc[mr][3]);
      *(float4*)&Cz[(long)(m0 + co0 + mr) * N + n0 + p0] = v;
    }
  }
}

// ================= masked BN =================
__global__ __launch_bounds__(TPB) void k_stats(const float* __restrict__ a,
                                               const float* __restrict__ m,
                                               float* __restrict__ stats, int vox) {
  int c = blockIdx.x;
  const float* ap = a + (long)c * vox;
  float s = 0.f, s2 = 0.f, sm = 0.f;
  for (int i = threadIdx.x; i < vox; i += TPB) {
    float mv = m[i];
    float v = ap[i] * mv;
    s += v; s2 += v * v; sm += mv;
  }
  __shared__ float sh0[TPB], sh1[TPB], sh2[TPB];
  sh0[threadIdx.x] = s; sh1[threadIdx.x] = s2; sh2[threadIdx.x] = sm;
  __syncthreads();
  for (int off = TPB / 2; off > 0; off >>= 1) {
    if (threadIdx.x < off) {
      sh0[threadIdx.x] += sh0[threadIdx.x + off];
      sh1[threadIdx.x] += sh1[threadIdx.x + off];
      sh2[threadIdx.x] += sh2[threadIdx.x + off];
    }
    __syncthreads();
  }
  if (threadIdx.x == 0) {
    float n = fmaxf(sh2[0], 1.f);
    float mu = sh0[0] / n;
    float var = fmaxf(sh1[0] / n - mu * mu, 0.f);
    stats[2 * c] = mu;
    stats[2 * c + 1] = rsqrtf(var + 1e-5f);
  }
}

__global__ __launch_bounds__(TPB) void k_apply(float* __restrict__ a,
                                               const float* __restrict__ m,
                                               const float* __restrict__ stats,
                                               int vox, long total) {
  long idx = blockIdx.x * (long)TPB + threadIdx.x;
  if (idx >= total) return;
  int c = (int)(idx / vox);
  int p = (int)(idx % vox);
  float v = (a[idx] - stats[2 * c]) * stats[2 * c + 1];
  a[idx] = fmaxf(v, 0.f) * m[p];
}

__global__ __launch_bounds__(TPB) void k_apply_out(const float* __restrict__ a,
                                                   const float* __restrict__ m,
                                                   const float* __restrict__ stats,
                                                   float* __restrict__ out,
                                                   int vox, long total) {
  long idx = blockIdx.x * (long)TPB + threadIdx.x;
  if (idx >= total) return;
  int c = (int)(idx / vox);
  int p = (int)(idx % vox);
  float v = (a[idx] - stats[2 * c]) * stats[2 * c + 1];
  out[idx] = fmaxf(v, 0.f) * m[p];
}

// ================= workspace layout (floats) =================
constexpr long o_m0 = 0;          // 64^3
constexpr long o_m1 = 262144;     // 32^3
constexpr long o_m2 = 294912;     // 16^3
constexpr long o_m3 = 299008;     // 8^3
constexpr long o_m4 = 299520;     // 4^3
constexpr long o_m5 = 299584;     // 2^3
constexpr long o_st = 299592;     // 2048 stats
constexpr long o_A  = 301696;     // 2M: xm -> split-K scratch -> u3 -> final preact
constexpr long o_B  = 2398848;    // 2M: a0 (feats0)
constexpr long o_C  = 4496000;    // 512K: a1 (feats1)
constexpr long o_D  = 5020288;    // 128K: a2 (feats2)
constexpr long o_E  = 5151360;    // 32K: a3 (feats3)
constexpr long o_F  = 5184128;    // 8K: a4
constexpr long o_G  = 5192320;    // 8K: a5
constexpr long o_H  = 5200512;    // 32K: u0
constexpr long o_I  = 5233280;    // 32K: f0
constexpr long o_J  = 5266048;    // 128K: u1
constexpr long o_K  = 5397120;    // 128K: f1
constexpr long o_L  = 5528192;    // 512K: u2
constexpr long o_M  = 6052480;    // 512K: f2
constexpr long o_N  = 6576768;    // 2M: f3
constexpr long o_fin = o_A;       // 4M: final preact overlays A+B (both dead)
// total: 8673920 floats = 33.1 MB

extern "C" void kernel_launch(void* const* d_in, const int* in_sizes, int n_in,
                              void* d_out, int out_size, void* d_ws, size_t ws_size,
                              hipStream_t stream) {
  const float* x      = (const float*)d_in[0];
  const float* mask   = (const float*)d_in[1];
  const float* w_enc0 = (const float*)d_in[2];
  const float* w_enc1 = (const float*)d_in[3];
  const float* w_enc2 = (const float*)d_in[4];
  const float* w_enc3 = (const float*)d_in[5];
  const float* w_btd  = (const float*)d_in[6];
  const float* w_btc  = (const float*)d_in[7];
  const float* w_up0  = (const float*)d_in[8];
  const float* w_fu0  = (const float*)d_in[9];
  const float* w_up1  = (const float*)d_in[10];
  const float* w_fu1  = (const float*)d_in[11];
  const float* w_up2  = (const float*)d_in[12];
  const float* w_fu2  = (const float*)d_in[13];
  const float* w_up3  = (const float*)d_in[14];
  const float* w_fu3  = (const float*)d_in[15];
  const float* w_fin  = (const float*)d_in[16];

  float* ws = (float*)d_ws;
  float* st = ws + o_st;
  float* scratch = ws + o_A;  // 2M floats; dead between enc0-read and up3-write
  float* out = (float*)d_out;

  auto blocks = [](long n) { return (unsigned)((n + TPB - 1) / TPB); };

  // masks
  k_mask0<<<blocks(262144), TPB, 0, stream>>>(mask, ws + o_m0, 262144);
  k_downmask<<<blocks(32768), TPB, 0, stream>>>(ws + o_m0, ws + o_m1, 32);
  k_downmask<<<blocks(4096), TPB, 0, stream>>>(ws + o_m1, ws + o_m2, 16);
  k_downmask<<<blocks(512), TPB, 0, stream>>>(ws + o_m2, ws + o_m3, 8);
  k_downmask<<<blocks(64), TPB, 0, stream>>>(ws + o_m3, ws + o_m4, 4);
  k_downmask<<<blocks(8), TPB, 0, stream>>>(ws + o_m4, ws + o_m5, 2);

  // masked input -> A
  k_maskx<<<blocks(8L * 262144), TPB, 0, stream>>>(x, ws + o_m0, ws + o_A,
                                                   8L * 262144, 262144);

  auto bnrelu = [&](float* a, const float* m, int C, int vox) {
    k_stats<<<C, TPB, 0, stream>>>(a, m, st, vox);
    long total = (long)C * vox;
    k_apply<<<blocks(total), TPB, 0, stream>>>(a, m, st, vox, total);
  };

#define GEMM(MT, MODE, A_, B1_, B2_, O_, M_, N_, K_, DIN_, DOUT_, C1_, Z_)   \
  do {                                                                        \
    int nch_ = ((K_) + 31) >> 5;                                              \
    int kper_ = (nch_ + (Z_) - 1) / (Z_);                                     \
    dim3 g_(((N_) + 63) / 64, (M_) / (MT), (Z_));                             \
    float* dst_ = ((Z_) > 1) ? scratch : (O_);                                \
    k_gemm<MT, MODE><<<g_, TPB, 0, stream>>>(A_, B1_, B2_, dst_, M_, N_, K_,  \
                                             DIN_, DOUT_, C1_, kper_);        \
    if ((Z_) > 1)                                                             \
      k_sumparts<<<blocks((long)(M_) * (N_)), TPB, 0, stream>>>(              \
          scratch, O_, (long)(M_) * (N_), (Z_));                              \
  } while (0)

  // ---------------- encoder ----------------
  GEMM(64, 0, w_enc0, ws + o_A, nullptr, ws + o_B, 64, 32768, 8 * 27, 64, 32, 0, 1);
  bnrelu(ws + o_B, ws + o_m1, 64, 32768);
  GEMM(64, 0, w_enc1, ws + o_B, nullptr, ws + o_C, 128, 4096, 64 * 27, 32, 16, 0, 2);
  bnrelu(ws + o_C, ws + o_m2, 128, 4096);
  GEMM(64, 0, w_enc2, ws + o_C, nullptr, ws + o_D, 256, 512, 128 * 27, 16, 8, 0, 8);
  bnrelu(ws + o_D, ws + o_m3, 256, 512);
  GEMM(64, 0, w_enc3, ws + o_D, nullptr, ws + o_E, 512, 64, 256 * 27, 8, 4, 0, 16);
  bnrelu(ws + o_E, ws + o_m4, 512, 64);

  // ---------------- bottleneck ----------------
  GEMM(64, 0, w_btd, ws + o_E, nullptr, ws + o_F, 1024, 8, 512 * 27, 4, 2, 0, 16);
  bnrelu(ws + o_F, ws + o_m5, 1024, 8);
  GEMM(64, 3, w_btc, ws + o_F, nullptr, ws + o_G, 1024, 8, 1024 * 27, 2, 2, 0, 32);
  bnrelu(ws + o_G, ws + o_m5, 1024, 8);

  // ---------------- decoder ----------------
  GEMM(64, 1, w_up0, ws + o_G, nullptr, ws + o_H, 512, 64, 1024 * 27, 2, 4, 0, 32);
  bnrelu(ws + o_H, ws + o_m4, 512, 64);
  GEMM(64, 2, w_fu0, ws + o_H, ws + o_E, ws + o_I, 512, 64, 1024, 4, 4, 512, 8);
  bnrelu(ws + o_I, ws + o_m4, 512, 64);

  GEMM(64, 1, w_up1, ws + o_I, nullptr, ws + o_J, 256, 512, 512 * 27, 4, 8, 0, 8);
  bnrelu(ws + o_J, ws + o_m3, 256, 512);
  GEMM(64, 2, w_fu1, ws + o_J, ws + o_D, ws + o_K, 256, 512, 512, 8, 8, 256, 4);
  bnrelu(ws + o_K, ws + o_m3, 256, 512);

  GEMM(64, 1, w_up2, ws + o_K, nullptr, ws + o_L, 128, 4096, 256 * 27, 8, 16, 0, 4);
  bnrelu(ws + o_L, ws + o_m2, 128, 4096);
  GEMM(64, 2, w_fu2, ws + o_L, ws + o_C, ws + o_M, 128, 4096, 256, 16, 16, 128, 1); // skip = a1
  bnrelu(ws + o_M, ws + o_m2, 128, 4096);

  GEMM(64, 1, w_up3, ws + o_M, nullptr, ws + o_A, 64, 32768, 128 * 27, 16, 32, 0, 1);
  bnrelu(ws + o_A, ws + o_m1, 64, 32768);
  GEMM(64, 2, w_fu3, ws + o_A, ws + o_B, ws + o_N, 64, 32768, 128, 32, 32, 64, 1); // skip = a0
  bnrelu(ws + o_N, ws + o_m1, 64, 32768);

  // ---------------- final up ----------------
  GEMM(16, 1, w_fin, ws + o_N, nullptr, ws + o_fin, 16, 262144, 64 * 27, 32, 64, 0, 1);
  k_stats<<<16, TPB, 0, stream>>>(ws + o_fin, ws + o_m0, st, 262144);
  long total = 16L * 262144;
  k_apply_out<<<blocks(total), TPB, 0, stream>>>(ws + o_fin, ws + o_m0, st, out,
                                                 262144, total);
#undef GEMM
}

// Round 7
// 2050.196 us; speedup vs baseline: 2.7413x; 1.1581x over previous
//
#include <hip/hip_runtime.h>
#include <hip/hip_bf16.h>

#define TPB 256

// ================= masks =================
__global__ __launch_bounds__(TPB) void k_mask0(const float* __restrict__ mask,
                                               float* __restrict__ m0, int n) {
  int i = blockIdx.x * TPB + threadIdx.x;
  if (i < n) m0[i] = (mask[i] < 0.1f) ? 1.0f : 0.0f;
}

__global__ __launch_bounds__(TPB) void k_downmask(const float* __restrict__ mi,
                                                  float* __restrict__ mo, int Dout) {
  int n = Dout * Dout * Dout;
  int idx = blockIdx.x * TPB + threadIdx.x;
  if (idx >= n) return;
  int Din = Dout * 2;
  int ox = idx % Dout, oy = (idx / Dout) % Dout, oz = idx / (Dout * Dout);
  float v = 0.f;
  for (int kz = 0; kz < 3; kz++) {
    int iz = 2 * oz + kz - 1; if ((unsigned)iz >= (unsigned)Din) continue;
    for (int ky = 0; ky < 3; ky++) {
      int iy = 2 * oy + ky - 1; if ((unsigned)iy >= (unsigned)Din) continue;
      for (int kx = 0; kx < 3; kx++) {
        int ix = 2 * ox + kx - 1; if ((unsigned)ix >= (unsigned)Din) continue;
        v = fmaxf(v, mi[(iz * Din + iy) * Din + ix]);
      }
    }
  }
  mo[idx] = v;
}

__global__ __launch_bounds__(TPB) void k_maskx(const float* __restrict__ x,
                                               const float* __restrict__ m,
                                               float* __restrict__ o,
                                               long total, int vox) {
  long i = blockIdx.x * (long)TPB + threadIdx.x;
  if (i < total) o[i] = x[i] * m[i % vox];
}

__global__ __launch_bounds__(TPB) void k_sumparts(const float* __restrict__ parts,
                                                  float* __restrict__ out,
                                                  long n, int s) {
  long i = blockIdx.x * (long)TPB + threadIdx.x;
  if (i >= n) return;
  float a = 0.f;
  for (int j = 0; j < s; j++) a += parts[(long)j * n + i];
  out[i] = a;
}

// sum split-K partials of one parity class and scatter to full-grid layout
__global__ __launch_bounds__(TPB) void k_sumscat(const float* __restrict__ parts,
                                                 float* __restrict__ out,
                                                 int M, int Np, int Z, int Dh,
                                                 int lgDh, int cls) {
  long i = blockIdx.x * (long)TPB + threadIdx.x;
  long tot = (long)M * Np;
  if (i >= tot) return;
  int co = (int)(i >> (3 * lgDh));
  int pp = (int)(i & (Np - 1));
  float s = 0.f;
  for (int z = 0; z < Z; z++) s += parts[((long)z * M + co) * Np + pp];
  int px = cls & 1, py = (cls >> 1) & 1, pz = (cls >> 2) & 1;
  int ox = pp & (Dh - 1), oy = (pp >> lgDh) & (Dh - 1), oz = pp >> (2 * lgDh);
  int DF = Dh * 2;
  long fc = ((long)(2 * oz + pz) * DF + (2 * oy + py)) * DF + (2 * ox + px);
  out[(long)co * ((long)DF * DF * DF) + fc] = s;
}

// ================= tiled implicit-GEMM, split-K, reg-prefetch =================
// C[M][N] = A[M][K] x B[K][N]
// MODE 0: conv k3 s2 p1    (k=(ci,27taps); i = 2o + k - 1)
// MODE 2: 1x1 fuse over concat(B1[C1], B2[K-C1])
// MODE 3: conv k3 s1 p1    (i = o + k - 1)
// MODE 4: convT parity class. C1 = packed parity (pz<<2|py<<1|px).
//         K = Cin*T, T = 2^(#even dims); per-dim: even -> taps {0,2}, i=o'-1+t;
//         odd -> tap 1, i=o'. All shifts, no division.
//         If gridDim.z==1: direct strided write into full grid (Dout=2*Din).
//         Else: contiguous [z][M][Np] partials (k_sumscat finishes).
template<int MT, int MODE>
__global__ __launch_bounds__(TPB) void k_gemm(const float* __restrict__ A,
                                              const float* __restrict__ B1,
                                              const float* __restrict__ B2,
                                              float* __restrict__ C,
                                              int M, int N, int K,
                                              int Din, int Dout, int C1,
                                              int kcPer) {
  constexpr int MR = MT / 16;
  constexpr int AEL = (MT == 64) ? 8 : 2;
  __shared__ __align__(16) float At[32][MT];
  __shared__ __align__(16) float Bt[32][64];

  const int t = threadIdx.x;
  const int n0 = blockIdx.x * 64;
  const int m0 = blockIdx.y * MT;

  const int p0 = (t & 15) * 4;
  const int co0 = (t >> 4) * MR;

  const int pb = t & 63;
  const int kb0 = (t >> 6) * 8;
  const int pp = n0 + pb;
  const int oxb = pp & (Dout - 1);
  const int oyb = (pp / Dout) & (Dout - 1);
  const int ozb = pp / (Dout * Dout);

  // MODE 4 parity decode
  int px = 0, py = 0, pz = 0, lgnx = 0, lgny = 0, lgT = 0, Cin = 0;
  if (MODE == 4) {
    px = C1 & 1; py = (C1 >> 1) & 1; pz = (C1 >> 2) & 1;
    lgnx = 1 - px; lgny = 1 - py;
    lgT = lgnx + lgny + (1 - pz);
    Cin = K >> lgT;
  }

  const int nch = (K + 31) >> 5;
  const int c0 = blockIdx.z * kcPer;
  int c1 = c0 + kcPer; if (c1 > nch) c1 = nch;

  float acc[MR][4];
#pragma unroll
  for (int a = 0; a < MR; a++)
#pragma unroll
    for (int b = 0; b < 4; b++) acc[a][b] = 0.f;

  float raf[AEL];
  float rb[8];
  // A staging map: MT64: co=t>>2, 8 consecutive k. MT16: co=t&15, 2 k (4-way not 16-way).
  const int co_a = (MT == 64) ? (t >> 2) : (t & 15);
  const int ka   = (MT == 64) ? ((t & 3) * 8) : ((t >> 4) * 2);
  const long arow = (long)(m0 + co_a) * K;

  auto loadA = [&](int c) {
    const int k0 = c << 5;
    if (MODE == 4) {
#pragma unroll
      for (int j = 0; j < AEL; j++) {
        const int kg = k0 + ka + j;
        float v = 0.f;
        if (kg < K) {
          int ci = kg >> lgT;
          int tt = kg & ((1 << lgT) - 1);
          int tx = tt & ((1 << lgnx) - 1); tt >>= lgnx;
          int ty = tt & ((1 << lgny) - 1);
          int tz = tt >> lgny;
          int kx = px ? 1 : (tx << 1);
          int ky = py ? 1 : (ty << 1);
          int kz = pz ? 1 : (tz << 1);
          v = A[((long)(m0 + co_a) * Cin + ci) * 27 + (kz * 3 + ky) * 3 + kx];
        }
        raf[j] = v;
      }
    } else if (MT == 64) {
#pragma unroll
      for (int j = 0; j < 2; j++) {
        const int kg = k0 + ka + j * 4;
        float4 v = (kg < K) ? *(const float4*)&A[arow + kg]
                            : make_float4(0.f, 0.f, 0.f, 0.f);
        raf[j * 4 + 0] = v.x; raf[j * 4 + 1] = v.y;
        raf[j * 4 + 2] = v.z; raf[j * 4 + 3] = v.w;
      }
    } else {
      const int kg = k0 + ka;
      raf[0] = (kg < K) ? A[arow + kg] : 0.f;
      raf[1] = (kg + 1 < K) ? A[arow + kg + 1] : 0.f;
    }
  };

  auto loadB = [&](int c) {
    const int k0 = c << 5;
#pragma unroll
    for (int j = 0; j < 8; j++) {
      const int kg = k0 + kb0 + j;
      float v = 0.f;
      if (kg < K && pp < N) {
        if (MODE == 2) {
          v = (kg < C1) ? B1[(long)kg * N + pp] : B2[(long)(kg - C1) * N + pp];
        } else if (MODE == 4) {
          int ci = kg >> lgT;
          int tt = kg & ((1 << lgT) - 1);
          int tx = tt & ((1 << lgnx) - 1); tt >>= lgnx;
          int ty = tt & ((1 << lgny) - 1);
          int tz = tt >> lgny;
          int ix = px ? oxb : (oxb - 1 + tx);
          int iy = py ? oyb : (oyb - 1 + ty);
          int iz = pz ? ozb : (ozb - 1 + tz);
          if ((ix | iy | iz) >= 0)
            v = B1[(long)ci * Din * Din * Din + ((long)iz * Din + iy) * Din + ix];
        } else {
          const int ci = kg / 27;
          const int tap = kg - ci * 27;
          const int kz = tap / 9;
          const int r9 = tap - kz * 9;
          const int ky = r9 / 3;
          const int kx = r9 - ky * 3;
          int iz, iy, ix;
          bool ok;
          if (MODE == 0) {
            iz = 2 * ozb + kz - 1; iy = 2 * oyb + ky - 1; ix = 2 * oxb + kx - 1;
            ok = (unsigned)iz < (unsigned)Din && (unsigned)iy < (unsigned)Din &&
                 (unsigned)ix < (unsigned)Din;
          } else { // MODE 3
            iz = ozb + kz - 1; iy = oyb + ky - 1; ix = oxb + kx - 1;
            ok = (unsigned)iz < (unsigned)Din && (unsigned)iy < (unsigned)Din &&
                 (unsigned)ix < (unsigned)Din;
          }
          if (ok)
            v = B1[(long)ci * Din * Din * Din + ((long)iz * Din + iy) * Din + ix];
        }
      }
      rb[j] = v;
    }
  };

  if (c0 < c1) { loadA(c0); loadB(c0); }

  for (int c = c0; c < c1; ++c) {
    __syncthreads();
#pragma unroll
    for (int j = 0; j < AEL; j++) At[ka + j][co_a] = raf[j];
#pragma unroll
    for (int j = 0; j < 8; j++) Bt[kb0 + j][pb] = rb[j];
    if (c + 1 < c1) { loadA(c + 1); loadB(c + 1); }
    __syncthreads();
#pragma unroll
    for (int kk = 0; kk < 32; ++kk) {
      const float4 b4 = *(const float4*)&Bt[kk][p0];
      if (MR == 4) {
        const float4 a4 = *(const float4*)&At[kk][co0];
        acc[0][0] += a4.x * b4.x; acc[0][1] += a4.x * b4.y;
        acc[0][2] += a4.x * b4.z; acc[0][3] += a4.x * b4.w;
        acc[1][0] += a4.y * b4.x; acc[1][1] += a4.y * b4.y;
        acc[1][2] += a4.y * b4.z; acc[1][3] += a4.y * b4.w;
        acc[2][0] += a4.z * b4.x; acc[2][1] += a4.z * b4.y;
        acc[2][2] += a4.z * b4.z; acc[2][3] += a4.z * b4.w;
        acc[3][0] += a4.w * b4.x; acc[3][1] += a4.w * b4.y;
        acc[3][2] += a4.w * b4.z; acc[3][3] += a4.w * b4.w;
      } else {
        const float a = At[kk][co0];
        acc[0][0] += a * b4.x; acc[0][1] += a * b4.y;
        acc[0][2] += a * b4.z; acc[0][3] += a * b4.w;
      }
    }
  }

  if (MODE == 4 && gridDim.z == 1) {
    // direct strided scatter into full grid
    const int lgD = 31 - __clz(Dout);
    const int DF = Din << 1;
    const long voxF = (long)DF * DF * DF;
#pragma unroll
    for (int mr = 0; mr < MR; mr++) {
#pragma unroll
      for (int e = 0; e < 4; e++) {
        int pp2 = n0 + p0 + e;
        if (pp2 < N) {
          int ox = pp2 & (Dout - 1), oy = (pp2 >> lgD) & (Dout - 1),
              oz = pp2 >> (2 * lgD);
          long fc = ((long)(2 * oz + pz) * DF + (2 * oy + py)) * DF +
                    (2 * ox + px);
          C[(long)(m0 + co0 + mr) * voxF + fc] = acc[mr][e];
        }
      }
    }
  } else {
    float* Cz = C + (long)blockIdx.z * ((long)M * N);
#pragma unroll
    for (int mr = 0; mr < MR; mr++) {
      if (n0 + p0 < N) {
        float4 v = make_float4(acc[mr][0], acc[mr][1], acc[mr][2], acc[mr][3]);
        *(float4*)&Cz[(long)(m0 + co0 + mr) * N + n0 + p0] = v;
      }
    }
  }
}

// ================= masked BN =================
__global__ __launch_bounds__(TPB) void k_stats(const float* __restrict__ a,
                                               const float* __restrict__ m,
                                               float* __restrict__ stats, int vox) {
  int c = blockIdx.x;
  const float* ap = a + (long)c * vox;
  float s = 0.f, s2 = 0.f, sm = 0.f;
  for (int i = threadIdx.x; i < vox; i += TPB) {
    float mv = m[i];
    float v = ap[i] * mv;
    s += v; s2 += v * v; sm += mv;
  }
  __shared__ float sh0[TPB], sh1[TPB], sh2[TPB];
  sh0[threadIdx.x] = s; sh1[threadIdx.x] = s2; sh2[threadIdx.x] = sm;
  __syncthreads();
  for (int off = TPB / 2; off > 0; off >>= 1) {
    if (threadIdx.x < off) {
      sh0[threadIdx.x] += sh0[threadIdx.x + off];
      sh1[threadIdx.x] += sh1[threadIdx.x + off];
      sh2[threadIdx.x] += sh2[threadIdx.x + off];
    }
    __syncthreads();
  }
  if (threadIdx.x == 0) {
    float n = fmaxf(sh2[0], 1.f);
    float mu = sh0[0] / n;
    float var = fmaxf(sh1[0] / n - mu * mu, 0.f);
    stats[2 * c] = mu;
    stats[2 * c + 1] = rsqrtf(var + 1e-5f);
  }
}

__global__ __launch_bounds__(TPB) void k_apply(float* __restrict__ a,
                                               const float* __restrict__ m,
                                               const float* __restrict__ stats,
                                               int vox, long total) {
  long idx = blockIdx.x * (long)TPB + threadIdx.x;
  if (idx >= total) return;
  int c = (int)(idx / vox);
  int p = (int)(idx % vox);
  float v = (a[idx] - stats[2 * c]) * stats[2 * c + 1];
  a[idx] = fmaxf(v, 0.f) * m[p];
}

__global__ __launch_bounds__(TPB) void k_apply_out(const float* __restrict__ a,
                                                   const float* __restrict__ m,
                                                   const float* __restrict__ stats,
                                                   float* __restrict__ out,
                                                   int vox, long total) {
  long idx = blockIdx.x * (long)TPB + threadIdx.x;
  if (idx >= total) return;
  int c = (int)(idx / vox);
  int p = (int)(idx % vox);
  float v = (a[idx] - stats[2 * c]) * stats[2 * c + 1];
  out[idx] = fmaxf(v, 0.f) * m[p];
}

// ================= workspace layout (floats) =================
constexpr long o_m0 = 0;          // 64^3
constexpr long o_m1 = 262144;     // 32^3
constexpr long o_m2 = 294912;     // 16^3
constexpr long o_m3 = 299008;     // 8^3
constexpr long o_m4 = 299520;     // 4^3
constexpr long o_m5 = 299584;     // 2^3
constexpr long o_st = 299592;     // 2048 stats
constexpr long o_A  = 301696;     // 2M: xm -> scratch -> u3 -> final preact
constexpr long o_B  = 2398848;    // 2M: a0 (feats0)
constexpr long o_C  = 4496000;    // 512K: a1 (feats1)
constexpr long o_D  = 5020288;    // 128K: a2 (feats2); +gap to o_M = up3 scratch
constexpr long o_E  = 5151360;    // 32K: a3 (feats3)
constexpr long o_F  = 5184128;    // 8K: a4
constexpr long o_G  = 5192320;    // 8K: a5
constexpr long o_H  = 5200512;    // 32K: u0
constexpr long o_I  = 5233280;    // 32K: f0
constexpr long o_J  = 5266048;    // 128K: u1
constexpr long o_K  = 5397120;    // 128K: f1
constexpr long o_L  = 5528192;    // 512K: u2
constexpr long o_M  = 6052480;    // 512K: f2
constexpr long o_N  = 6576768;    // 2M: f3
constexpr long o_fin = o_A;       // 4M: final preact overlays A+B (both dead)

extern "C" void kernel_launch(void* const* d_in, const int* in_sizes, int n_in,
                              void* d_out, int out_size, void* d_ws, size_t ws_size,
                              hipStream_t stream) {
  const float* x      = (const float*)d_in[0];
  const float* mask   = (const float*)d_in[1];
  const float* w_enc0 = (const float*)d_in[2];
  const float* w_enc1 = (const float*)d_in[3];
  const float* w_enc2 = (const float*)d_in[4];
  const float* w_enc3 = (const float*)d_in[5];
  const float* w_btd  = (const float*)d_in[6];
  const float* w_btc  = (const float*)d_in[7];
  const float* w_up0  = (const float*)d_in[8];
  const float* w_fu0  = (const float*)d_in[9];
  const float* w_up1  = (const float*)d_in[10];
  const float* w_fu1  = (const float*)d_in[11];
  const float* w_up2  = (const float*)d_in[12];
  const float* w_fu2  = (const float*)d_in[13];
  const float* w_up3  = (const float*)d_in[14];
  const float* w_fu3  = (const float*)d_in[15];
  const float* w_fin  = (const float*)d_in[16];

  float* ws = (float*)d_ws;
  float* st = ws + o_st;
  float* out = (float*)d_out;

  auto blocks = [](long n) { return (unsigned)((n + TPB - 1) / TPB); };

  // masks
  k_mask0<<<blocks(262144), TPB, 0, stream>>>(mask, ws + o_m0, 262144);
  k_downmask<<<blocks(32768), TPB, 0, stream>>>(ws + o_m0, ws + o_m1, 32);
  k_downmask<<<blocks(4096), TPB, 0, stream>>>(ws + o_m1, ws + o_m2, 16);
  k_downmask<<<blocks(512), TPB, 0, stream>>>(ws + o_m2, ws + o_m3, 8);
  k_downmask<<<blocks(64), TPB, 0, stream>>>(ws + o_m3, ws + o_m4, 4);
  k_downmask<<<blocks(8), TPB, 0, stream>>>(ws + o_m4, ws + o_m5, 2);

  // masked input -> A
  k_maskx<<<blocks(8L * 262144), TPB, 0, stream>>>(x, ws + o_m0, ws + o_A,
                                                   8L * 262144, 262144);

  auto bnrelu = [&](float* a, const float* m, int C, int vox) {
    k_stats<<<C, TPB, 0, stream>>>(a, m, st, vox);
    long total = (long)C * vox;
    k_apply<<<blocks(total), TPB, 0, stream>>>(a, m, st, vox, total);
  };

#define GEMM(MT, MODE, A_, B1_, B2_, O_, M_, N_, K_, DIN_, DOUT_, C1_, Z_)   \
  do {                                                                        \
    int nch_ = ((K_) + 31) >> 5;                                              \
    int kper_ = (nch_ + (Z_) - 1) / (Z_);                                     \
    dim3 g_(((N_) + 63) / 64, (M_) / (MT), (Z_));                             \
    float* dst_ = ((Z_) > 1) ? (ws + o_A) : (O_);                             \
    k_gemm<MT, MODE><<<g_, TPB, 0, stream>>>(A_, B1_, B2_, dst_, M_, N_, K_,  \
                                             DIN_, DOUT_, C1_, kper_);        \
    if ((Z_) > 1)                                                             \
      k_sumparts<<<blocks((long)(M_) * (N_)), TPB, 0, stream>>>(              \
          ws + o_A, O_, (long)(M_) * (N_), (Z_));                             \
  } while (0)

  // parity-decomposed convT: 8 classes, each a dense shift-only GEMM
  auto convTpar = [&](const float* w, const float* in, float* o, int M, int Cin,
                      int Dh, float* scr, long scrCap) {
    int lgDh = 31 - __builtin_clz(Dh);
    int Np = Dh * Dh * Dh;
    for (int cls = 0; cls < 8; ++cls) {
      int px = cls & 1, py = (cls >> 1) & 1, pz = (cls >> 2) & 1;
      int T = 1 << ((1 - px) + (1 - py) + (1 - pz));
      int K = Cin * T;
      int nch = (K + 31) >> 5;
      int Z = nch / 8; if (Z < 1) Z = 1; if (Z > 32) Z = 32;
      long cap = scrCap / ((long)M * Np);
      if (Z > cap) Z = (int)cap; if (Z < 1) Z = 1;
      int kper = (nch + Z - 1) / Z;
      dim3 g((Np + 63) / 64, M / 64, Z);
      if (Z == 1) {
        k_gemm<64, 4><<<g, TPB, 0, stream>>>(w, in, nullptr, o, M, Np, K,
                                             Dh, Dh, cls, kper);
      } else {
        k_gemm<64, 4><<<g, TPB, 0, stream>>>(w, in, nullptr, scr, M, Np, K,
                                             Dh, Dh, cls, kper);
        k_sumscat<<<blocks((long)M * Np), TPB, 0, stream>>>(scr, o, M, Np, Z,
                                                            Dh, lgDh, cls);
      }
    }
  };

  // ---------------- encoder ----------------
  GEMM(64, 0, w_enc0, ws + o_A, nullptr, ws + o_B, 64, 32768, 8 * 27, 64, 32, 0, 1);
  bnrelu(ws + o_B, ws + o_m1, 64, 32768);
  GEMM(64, 0, w_enc1, ws + o_B, nullptr, ws + o_C, 128, 4096, 64 * 27, 32, 16, 0, 2);
  bnrelu(ws + o_C, ws + o_m2, 128, 4096);
  GEMM(64, 0, w_enc2, ws + o_C, nullptr, ws + o_D, 256, 512, 128 * 27, 16, 8, 0, 8);
  bnrelu(ws + o_D, ws + o_m3, 256, 512);
  GEMM(64, 0, w_enc3, ws + o_D, nullptr, ws + o_E, 512, 64, 256 * 27, 8, 4, 0, 16);
  bnrelu(ws + o_E, ws + o_m4, 512, 64);

  // ---------------- bottleneck ----------------
  GEMM(64, 0, w_btd, ws + o_E, nullptr, ws + o_F, 1024, 8, 512 * 27, 4, 2, 0, 16);
  bnrelu(ws + o_F, ws + o_m5, 1024, 8);
  GEMM(64, 3, w_btc, ws + o_F, nullptr, ws + o_G, 1024, 8, 1024 * 27, 2, 2, 0, 32);
  bnrelu(ws + o_G, ws + o_m5, 1024, 8);

  // ---------------- decoder ----------------
  convTpar(w_up0, ws + o_G, ws + o_H, 512, 1024, 2, ws + o_A, 2097152);
  bnrelu(ws + o_H, ws + o_m4, 512, 64);
  GEMM(64, 2, w_fu0, ws + o_H, ws + o_E, ws + o_I, 512, 64, 1024, 4, 4, 512, 8);
  bnrelu(ws + o_I, ws + o_m4, 512, 64);

  convTpar(w_up1, ws + o_I, ws + o_J, 256, 512, 4, ws + o_A, 2097152);
  bnrelu(ws + o_J, ws + o_m3, 256, 512);
  GEMM(64, 2, w_fu1, ws + o_J, ws + o_D, ws + o_K, 256, 512, 512, 8, 8, 256, 4);
  bnrelu(ws + o_K, ws + o_m3, 256, 512);

  convTpar(w_up2, ws + o_K, ws + o_L, 128, 256, 8, ws + o_A, 2097152);
  bnrelu(ws + o_L, ws + o_m2, 128, 4096);
  GEMM(64, 2, w_fu2, ws + o_L, ws + o_C, ws + o_M, 128, 4096, 256, 16, 16, 128, 1);
  bnrelu(ws + o_M, ws + o_m2, 128, 4096);

  // up3 writes o_A; scratch must avoid o_A and live o_M -> use o_D..o_M gap
  convTpar(w_up3, ws + o_M, ws + o_A, 64, 128, 16, ws + o_D, 1032192);
  bnrelu(ws + o_A, ws + o_m1, 64, 32768);
  GEMM(64, 2, w_fu3, ws + o_A, ws + o_B, ws + o_N, 64, 32768, 128, 32, 32, 64, 1);
  bnrelu(ws + o_N, ws + o_m1, 64, 32768);

  // ---------------- final up (M=16): 8 parity classes, Z=1 direct ----------------
  for (int cls = 0; cls < 8; ++cls) {
    int px = cls & 1, py = (cls >> 1) & 1, pz = (cls >> 2) & 1;
    int T = 1 << ((1 - px) + (1 - py) + (1 - pz));
    int K = 64 * T;
    int nch = (K + 31) >> 5;
    dim3 g((32768 + 63) / 64, 1, 1);
    k_gemm<16, 4><<<g, TPB, 0, stream>>>(w_fin, ws + o_N, nullptr, ws + o_fin,
                                         16, 32768, K, 32, 32, cls, nch);
  }
  k_stats<<<16, TPB, 0, stream>>>(ws + o_fin, ws + o_m0, st, 262144);
  long total = 16L * 262144;
  k_apply_out<<<blocks(total), TPB, 0, stream>>>(ws + o_fin, ws + o_m0, st, out,
                                                 262144, total);
#undef GEMM
}

// Round 8
// 1675.657 us; speedup vs baseline: 3.3540x; 1.2235x over previous
//
#include <hip/hip_runtime.h>
#include <hip/hip_bf16.h>

#define TPB 256

// ================= masks =================
__global__ __launch_bounds__(TPB) void k_mask0(const float* __restrict__ mask,
                                               float* __restrict__ m0, int n) {
  int i = blockIdx.x * TPB + threadIdx.x;
  if (i < n) m0[i] = (mask[i] < 0.1f) ? 1.0f : 0.0f;
}

__global__ __launch_bounds__(TPB) void k_downmask(const float* __restrict__ mi,
                                                  float* __restrict__ mo, int Dout) {
  int n = Dout * Dout * Dout;
  int idx = blockIdx.x * TPB + threadIdx.x;
  if (idx >= n) return;
  int Din = Dout * 2;
  int ox = idx % Dout, oy = (idx / Dout) % Dout, oz = idx / (Dout * Dout);
  float v = 0.f;
  for (int kz = 0; kz < 3; kz++) {
    int iz = 2 * oz + kz - 1; if ((unsigned)iz >= (unsigned)Din) continue;
    for (int ky = 0; ky < 3; ky++) {
      int iy = 2 * oy + ky - 1; if ((unsigned)iy >= (unsigned)Din) continue;
      for (int kx = 0; kx < 3; kx++) {
        int ix = 2 * ox + kx - 1; if ((unsigned)ix >= (unsigned)Din) continue;
        v = fmaxf(v, mi[(iz * Din + iy) * Din + ix]);
      }
    }
  }
  mo[idx] = v;
}

__global__ __launch_bounds__(TPB) void k_maskx(const float* __restrict__ x,
                                               const float* __restrict__ m,
                                               float* __restrict__ o,
                                               long total, int vox) {
  long i = blockIdx.x * (long)TPB + threadIdx.x;
  if (i < total) o[i] = x[i] * m[i % vox];
}

__global__ __launch_bounds__(TPB) void k_sumparts(const float* __restrict__ parts,
                                                  float* __restrict__ out,
                                                  long n, int s) {
  long i = blockIdx.x * (long)TPB + threadIdx.x;
  if (i >= n) return;
  float a = 0.f;
  for (int j = 0; j < s; j++) a += parts[(long)j * n + i];
  out[i] = a;
}

// sum split-K partials of one parity class and scatter to full-grid layout
__global__ __launch_bounds__(TPB) void k_sumscat(const float* __restrict__ parts,
                                                 float* __restrict__ out,
                                                 int M, int Np, int Z, int Dh,
                                                 int lgDh, int cls) {
  long i = blockIdx.x * (long)TPB + threadIdx.x;
  long tot = (long)M * Np;
  if (i >= tot) return;
  int co = (int)(i >> (3 * lgDh));
  int pp = (int)(i & (Np - 1));
  float s = 0.f;
  for (int z = 0; z < Z; z++) s += parts[((long)z * M + co) * Np + pp];
  int px = cls & 1, py = (cls >> 1) & 1, pz = (cls >> 2) & 1;
  int ox = pp & (Dh - 1), oy = (pp >> lgDh) & (Dh - 1), oz = pp >> (2 * lgDh);
  int DF = Dh * 2;
  long fc = ((long)(2 * oz + pz) * DF + (2 * oy + py)) * DF + (2 * ox + px);
  out[(long)co * ((long)DF * DF * DF) + fc] = s;
}

// ================= tiled implicit-GEMM, split-K, reg-prefetch =================
// C[M][N] = A[M][K] x B[K][N]
// MODE 0: conv k3 s2 p1    (k=(ci,27taps); i = 2o + k - 1)
// MODE 2: 1x1 fuse over concat(B1[C1], B2[K-C1])
// MODE 3: conv k3 s1 p1    (i = o + k - 1)
// MODE 4: convT parity class. C1 = packed parity (pz<<2|py<<1|px).
template<int MT, int MODE>
__global__ __launch_bounds__(TPB) void k_gemm(const float* __restrict__ A,
                                              const float* __restrict__ B1,
                                              const float* __restrict__ B2,
                                              float* __restrict__ C,
                                              int M, int N, int K,
                                              int Din, int Dout, int C1,
                                              int kcPer) {
  constexpr int MR = MT / 16;
  constexpr int AEL = (MT == 64) ? 8 : 2;
  __shared__ __align__(16) float At[32][MT];
  __shared__ __align__(16) float Bt[32][64];

  const int t = threadIdx.x;
  const int n0 = blockIdx.x * 64;
  const int m0 = blockIdx.y * MT;

  const int p0 = (t & 15) * 4;
  const int co0 = (t >> 4) * MR;

  const int pb = t & 63;
  const int kb0 = (t >> 6) * 8;
  const int pp = n0 + pb;
  const int oxb = pp & (Dout - 1);
  const int oyb = (pp / Dout) & (Dout - 1);
  const int ozb = pp / (Dout * Dout);

  int px = 0, py = 0, pz = 0, lgnx = 0, lgny = 0, lgT = 0, Cin = 0;
  if (MODE == 4) {
    px = C1 & 1; py = (C1 >> 1) & 1; pz = (C1 >> 2) & 1;
    lgnx = 1 - px; lgny = 1 - py;
    lgT = lgnx + lgny + (1 - pz);
    Cin = K >> lgT;
  }

  const int nch = (K + 31) >> 5;
  const int c0 = blockIdx.z * kcPer;
  int c1 = c0 + kcPer; if (c1 > nch) c1 = nch;

  float acc[MR][4];
#pragma unroll
  for (int a = 0; a < MR; a++)
#pragma unroll
    for (int b = 0; b < 4; b++) acc[a][b] = 0.f;

  float raf[AEL];
  float rb[8];
  const int co_a = (MT == 64) ? (t >> 2) : (t & 15);
  const int ka   = (MT == 64) ? ((t & 3) * 8) : ((t >> 4) * 2);
  const long arow = (long)(m0 + co_a) * K;

  auto loadA = [&](int c) {
    const int k0 = c << 5;
    if (MODE == 4) {
#pragma unroll
      for (int j = 0; j < AEL; j++) {
        const int kg = k0 + ka + j;
        float v = 0.f;
        if (kg < K) {
          int ci = kg >> lgT;
          int tt = kg & ((1 << lgT) - 1);
          int tx = tt & ((1 << lgnx) - 1); tt >>= lgnx;
          int ty = tt & ((1 << lgny) - 1);
          int tz = tt >> lgny;
          int kx = px ? 1 : (tx << 1);
          int ky = py ? 1 : (ty << 1);
          int kz = pz ? 1 : (tz << 1);
          v = A[((long)(m0 + co_a) * Cin + ci) * 27 + (kz * 3 + ky) * 3 + kx];
        }
        raf[j] = v;
      }
    } else if (MT == 64) {
#pragma unroll
      for (int j = 0; j < 2; j++) {
        const int kg = k0 + ka + j * 4;
        float4 v = (kg < K) ? *(const float4*)&A[arow + kg]
                            : make_float4(0.f, 0.f, 0.f, 0.f);
        raf[j * 4 + 0] = v.x; raf[j * 4 + 1] = v.y;
        raf[j * 4 + 2] = v.z; raf[j * 4 + 3] = v.w;
      }
    } else {
      const int kg = k0 + ka;
      raf[0] = (kg < K) ? A[arow + kg] : 0.f;
      raf[1] = (kg + 1 < K) ? A[arow + kg + 1] : 0.f;
    }
  };

  auto loadB = [&](int c) {
    const int k0 = c << 5;
#pragma unroll
    for (int j = 0; j < 8; j++) {
      const int kg = k0 + kb0 + j;
      float v = 0.f;
      if (kg < K && pp < N) {
        if (MODE == 2) {
          v = (kg < C1) ? B1[(long)kg * N + pp] : B2[(long)(kg - C1) * N + pp];
        } else if (MODE == 4) {
          int ci = kg >> lgT;
          int tt = kg & ((1 << lgT) - 1);
          int tx = tt & ((1 << lgnx) - 1); tt >>= lgnx;
          int ty = tt & ((1 << lgny) - 1);
          int tz = tt >> lgny;
          int ix = px ? oxb : (oxb - 1 + tx);
          int iy = py ? oyb : (oyb - 1 + ty);
          int iz = pz ? ozb : (ozb - 1 + tz);
          if ((ix | iy | iz) >= 0)
            v = B1[(long)ci * Din * Din * Din + ((long)iz * Din + iy) * Din + ix];
        } else {
          const int ci = kg / 27;
          const int tap = kg - ci * 27;
          const int kz = tap / 9;
          const int r9 = tap - kz * 9;
          const int ky = r9 / 3;
          const int kx = r9 - ky * 3;
          int iz, iy, ix;
          bool ok;
          if (MODE == 0) {
            iz = 2 * ozb + kz - 1; iy = 2 * oyb + ky - 1; ix = 2 * oxb + kx - 1;
            ok = (unsigned)iz < (unsigned)Din && (unsigned)iy < (unsigned)Din &&
                 (unsigned)ix < (unsigned)Din;
          } else { // MODE 3
            iz = ozb + kz - 1; iy = oyb + ky - 1; ix = oxb + kx - 1;
            ok = (unsigned)iz < (unsigned)Din && (unsigned)iy < (unsigned)Din &&
                 (unsigned)ix < (unsigned)Din;
          }
          if (ok)
            v = B1[(long)ci * Din * Din * Din + ((long)iz * Din + iy) * Din + ix];
        }
      }
      rb[j] = v;
    }
  };

  if (c0 < c1) { loadA(c0); loadB(c0); }

  for (int c = c0; c < c1; ++c) {
    __syncthreads();
#pragma unroll
    for (int j = 0; j < AEL; j++) At[ka + j][co_a] = raf[j];
#pragma unroll
    for (int j = 0; j < 8; j++) Bt[kb0 + j][pb] = rb[j];
    if (c + 1 < c1) { loadA(c + 1); loadB(c + 1); }
    __syncthreads();
#pragma unroll
    for (int kk = 0; kk < 32; ++kk) {
      const float4 b4 = *(const float4*)&Bt[kk][p0];
      if (MR == 4) {
        const float4 a4 = *(const float4*)&At[kk][co0];
        acc[0][0] += a4.x * b4.x; acc[0][1] += a4.x * b4.y;
        acc[0][2] += a4.x * b4.z; acc[0][3] += a4.x * b4.w;
        acc[1][0] += a4.y * b4.x; acc[1][1] += a4.y * b4.y;
        acc[1][2] += a4.y * b4.z; acc[1][3] += a4.y * b4.w;
        acc[2][0] += a4.z * b4.x; acc[2][1] += a4.z * b4.y;
        acc[2][2] += a4.z * b4.z; acc[2][3] += a4.z * b4.w;
        acc[3][0] += a4.w * b4.x; acc[3][1] += a4.w * b4.y;
        acc[3][2] += a4.w * b4.z; acc[3][3] += a4.w * b4.w;
      } else {
        const float a = At[kk][co0];
        acc[0][0] += a * b4.x; acc[0][1] += a * b4.y;
        acc[0][2] += a * b4.z; acc[0][3] += a * b4.w;
      }
    }
  }

  if (MODE == 4 && gridDim.z == 1) {
    const int lgD = 31 - __clz(Dout);
    const int DF = Din << 1;
    const long voxF = (long)DF * DF * DF;
#pragma unroll
    for (int mr = 0; mr < MR; mr++) {
#pragma unroll
      for (int e = 0; e < 4; e++) {
        int pp2 = n0 + p0 + e;
        if (pp2 < N) {
          int ox = pp2 & (Dout - 1), oy = (pp2 >> lgD) & (Dout - 1),
              oz = pp2 >> (2 * lgD);
          long fc = ((long)(2 * oz + pz) * DF + (2 * oy + py)) * DF +
                    (2 * ox + px);
          C[(long)(m0 + co0 + mr) * voxF + fc] = acc[mr][e];
        }
      }
    }
  } else {
    float* Cz = C + (long)blockIdx.z * ((long)M * N);
#pragma unroll
    for (int mr = 0; mr < MR; mr++) {
      if (n0 + p0 < N) {
        float4 v = make_float4(acc[mr][0], acc[mr][1], acc[mr][2], acc[mr][3]);
        *(float4*)&Cz[(long)(m0 + co0 + mr) * N + n0 + p0] = v;
      }
    }
  }
}

// ================= hierarchical masked BN stats =================
// stage 1: block (s=blockIdx.x of S, c=blockIdx.y of C) reduces its slice.
// part[(c*S+s)*2] = {sum, sumsq}; partM[s] = mask count (c==0 blocks only).
__global__ __launch_bounds__(TPB) void k_stats1(const float* __restrict__ a,
                                                const float* __restrict__ m,
                                                float* __restrict__ part,
                                                float* __restrict__ partM,
                                                int vox, int chunk) {
  const int s = blockIdx.x, c = blockIdx.y;
  const float* ap = a + (long)c * vox + (long)s * chunk;
  const float* mp = m + (long)s * chunk;
  float s0 = 0.f, s1 = 0.f, sm = 0.f;
  for (int i = threadIdx.x; i < chunk; i += TPB) {
    float mv = mp[i];
    float v = ap[i] * mv;
    s0 += v; s1 += v * v; sm += mv;
  }
  __shared__ float sh0[TPB], sh1[TPB], sh2[TPB];
  sh0[threadIdx.x] = s0; sh1[threadIdx.x] = s1; sh2[threadIdx.x] = sm;
  __syncthreads();
  for (int off = TPB / 2; off > 0; off >>= 1) {
    if (threadIdx.x < off) {
      sh0[threadIdx.x] += sh0[threadIdx.x + off];
      sh1[threadIdx.x] += sh1[threadIdx.x + off];
      sh2[threadIdx.x] += sh2[threadIdx.x + off];
    }
    __syncthreads();
  }
  if (threadIdx.x == 0) {
    const int S = gridDim.x;
    part[(c * S + s) * 2] = sh0[0];
    part[(c * S + s) * 2 + 1] = sh1[0];
    if (c == 0) partM[s] = sh2[0];
  }
}

// stage 2: one wave per channel reduces S partials -> stats {mu, rstd}
__global__ __launch_bounds__(64) void k_stats2(const float* __restrict__ part,
                                               const float* __restrict__ partM,
                                               float* __restrict__ stats, int S) {
  const int c = blockIdx.x, t = threadIdx.x;
  float s0 = 0.f, s1 = 0.f, sm = 0.f;
  for (int s = t; s < S; s += 64) {
    s0 += part[(c * S + s) * 2];
    s1 += part[(c * S + s) * 2 + 1];
    sm += partM[s];
  }
  for (int off = 32; off > 0; off >>= 1) {
    s0 += __shfl_down(s0, off);
    s1 += __shfl_down(s1, off);
    sm += __shfl_down(sm, off);
  }
  if (t == 0) {
    float n = fmaxf(sm, 1.f);
    float mu = s0 / n;
    float var = fmaxf(s1 / n - mu * mu, 0.f);
    stats[2 * c] = mu;
    stats[2 * c + 1] = rsqrtf(var + 1e-5f);
  }
}

__global__ __launch_bounds__(TPB) void k_apply(float* __restrict__ a,
                                               const float* __restrict__ m,
                                               const float* __restrict__ stats,
                                               int vox, long total) {
  long idx = blockIdx.x * (long)TPB + threadIdx.x;
  if (idx >= total) return;
  int c = (int)(idx / vox);
  int p = (int)(idx % vox);
  float v = (a[idx] - stats[2 * c]) * stats[2 * c + 1];
  a[idx] = fmaxf(v, 0.f) * m[p];
}

__global__ __launch_bounds__(TPB) void k_apply_out(const float* __restrict__ a,
                                                   const float* __restrict__ m,
                                                   const float* __restrict__ stats,
                                                   float* __restrict__ out,
                                                   int vox, long total) {
  long idx = blockIdx.x * (long)TPB + threadIdx.x;
  if (idx >= total) return;
  int c = (int)(idx / vox);
  int p = (int)(idx % vox);
  float v = (a[idx] - stats[2 * c]) * stats[2 * c + 1];
  out[idx] = fmaxf(v, 0.f) * m[p];
}

// ================= workspace layout (floats) =================
constexpr long o_m0 = 0;          // 64^3
constexpr long o_m1 = 262144;     // 32^3
constexpr long o_m2 = 294912;     // 16^3
constexpr long o_m3 = 299008;     // 8^3
constexpr long o_m4 = 299520;     // 4^3
constexpr long o_m5 = 299584;     // 2^3
constexpr long o_st = 299592;     // 2048 stats
constexpr long o_A  = 301696;     // 2M: xm -> scratch -> u3 -> final preact
constexpr long o_B  = 2398848;    // 2M: a0 (feats0)
constexpr long o_C  = 4496000;    // 512K: a1 (feats1)
constexpr long o_D  = 5020288;    // 128K: a2 (feats2); +gap to o_M = up3 scratch
constexpr long o_E  = 5151360;    // 32K: a3 (feats3)
constexpr long o_F  = 5184128;    // 8K: a4
constexpr long o_G  = 5192320;    // 8K: a5
constexpr long o_H  = 5200512;    // 32K: u0
constexpr long o_I  = 5233280;    // 32K: f0
constexpr long o_J  = 5266048;    // 128K: u1
constexpr long o_K  = 5397120;    // 128K: f1
constexpr long o_L  = 5528192;    // 512K: u2
constexpr long o_M  = 6052480;    // 512K: f2
constexpr long o_N  = 6576768;    // 2M: f3
constexpr long o_P  = 8673920;    // 16K: BN partials
constexpr long o_PM = 8690304;    // 64: mask-count partials
constexpr long o_fin = o_A;       // 4M: final preact overlays A+B (both dead)
// total: 8690368 floats = 33.2 MB

extern "C" void kernel_launch(void* const* d_in, const int* in_sizes, int n_in,
                              void* d_out, int out_size, void* d_ws, size_t ws_size,
                              hipStream_t stream) {
  const float* x      = (const float*)d_in[0];
  const float* mask   = (const float*)d_in[1];
  const float* w_enc0 = (const float*)d_in[2];
  const float* w_enc1 = (const float*)d_in[3];
  const float* w_enc2 = (const float*)d_in[4];
  const float* w_enc3 = (const float*)d_in[5];
  const float* w_btd  = (const float*)d_in[6];
  const float* w_btc  = (const float*)d_in[7];
  const float* w_up0  = (const float*)d_in[8];
  const float* w_fu0  = (const float*)d_in[9];
  const float* w_up1  = (const float*)d_in[10];
  const float* w_fu1  = (const float*)d_in[11];
  const float* w_up2  = (const float*)d_in[12];
  const float* w_fu2  = (const float*)d_in[13];
  const float* w_up3  = (const float*)d_in[14];
  const float* w_fu3  = (const float*)d_in[15];
  const float* w_fin  = (const float*)d_in[16];

  float* ws = (float*)d_ws;
  float* st = ws + o_st;
  float* out = (float*)d_out;

  auto blocks = [](long n) { return (unsigned)((n + TPB - 1) / TPB); };

  // masks
  k_mask0<<<blocks(262144), TPB, 0, stream>>>(mask, ws + o_m0, 262144);
  k_downmask<<<blocks(32768), TPB, 0, stream>>>(ws + o_m0, ws + o_m1, 32);
  k_downmask<<<blocks(4096), TPB, 0, stream>>>(ws + o_m1, ws + o_m2, 16);
  k_downmask<<<blocks(512), TPB, 0, stream>>>(ws + o_m2, ws + o_m3, 8);
  k_downmask<<<blocks(64), TPB, 0, stream>>>(ws + o_m3, ws + o_m4, 4);
  k_downmask<<<blocks(8), TPB, 0, stream>>>(ws + o_m4, ws + o_m5, 2);

  // masked input -> A
  k_maskx<<<blocks(8L * 262144), TPB, 0, stream>>>(x, ws + o_m0, ws + o_A,
                                                   8L * 262144, 262144);

  auto stats = [&](const float* a, const float* m, int C, int vox) {
    int S = vox / TPB; if (S < 1) S = 1; if (S > 64) S = 64;
    int chunk = vox / S;
    dim3 g(S, C);
    k_stats1<<<g, TPB, 0, stream>>>(a, m, ws + o_P, ws + o_PM, vox, chunk);
    k_stats2<<<C, 64, 0, stream>>>(ws + o_P, ws + o_PM, st, S);
  };
  auto bnrelu = [&](float* a, const float* m, int C, int vox) {
    stats(a, m, C, vox);
    long total = (long)C * vox;
    k_apply<<<blocks(total), TPB, 0, stream>>>(a, m, st, vox, total);
  };

#define GEMM(MT, MODE, A_, B1_, B2_, O_, M_, N_, K_, DIN_, DOUT_, C1_, Z_)   \
  do {                                                                        \
    int nch_ = ((K_) + 31) >> 5;                                              \
    int kper_ = (nch_ + (Z_) - 1) / (Z_);                                     \
    dim3 g_(((N_) + 63) / 64, (M_) / (MT), (Z_));                             \
    float* dst_ = ((Z_) > 1) ? (ws + o_A) : (O_);                             \
    k_gemm<MT, MODE><<<g_, TPB, 0, stream>>>(A_, B1_, B2_, dst_, M_, N_, K_,  \
                                             DIN_, DOUT_, C1_, kper_);        \
    if ((Z_) > 1)                                                             \
      k_sumparts<<<blocks((long)(M_) * (N_)), TPB, 0, stream>>>(              \
          ws + o_A, O_, (long)(M_) * (N_), (Z_));                             \
  } while (0)

  // parity-decomposed convT: 8 classes, each a dense shift-only GEMM
  auto convTpar = [&](const float* w, const float* in, float* o, int M, int Cin,
                      int Dh, float* scr, long scrCap) {
    int lgDh = 31 - __builtin_clz(Dh);
    int Np = Dh * Dh * Dh;
    for (int cls = 0; cls < 8; ++cls) {
      int px = cls & 1, py = (cls >> 1) & 1, pz = (cls >> 2) & 1;
      int T = 1 << ((1 - px) + (1 - py) + (1 - pz));
      int K = Cin * T;
      int nch = (K + 31) >> 5;
      int Z = nch / 8; if (Z < 1) Z = 1; if (Z > 32) Z = 32;
      long cap = scrCap / ((long)M * Np);
      if (Z > cap) Z = (int)cap; if (Z < 1) Z = 1;
      int kper = (nch + Z - 1) / Z;
      dim3 g((Np + 63) / 64, M / 64, Z);
      if (Z == 1) {
        k_gemm<64, 4><<<g, TPB, 0, stream>>>(w, in, nullptr, o, M, Np, K,
                                             Dh, Dh, cls, kper);
      } else {
        k_gemm<64, 4><<<g, TPB, 0, stream>>>(w, in, nullptr, scr, M, Np, K,
                                             Dh, Dh, cls, kper);
        k_sumscat<<<blocks((long)M * Np), TPB, 0, stream>>>(scr, o, M, Np, Z,
                                                            Dh, lgDh, cls);
      }
    }
  };

  // ---------------- encoder ----------------
  GEMM(64, 0, w_enc0, ws + o_A, nullptr, ws + o_B, 64, 32768, 8 * 27, 64, 32, 0, 1);
  bnrelu(ws + o_B, ws + o_m1, 64, 32768);
  GEMM(64, 0, w_enc1, ws + o_B, nullptr, ws + o_C, 128, 4096, 64 * 27, 32, 16, 0, 2);
  bnrelu(ws + o_C, ws + o_m2, 128, 4096);
  GEMM(64, 0, w_enc2, ws + o_C, nullptr, ws + o_D, 256, 512, 128 * 27, 16, 8, 0, 8);
  bnrelu(ws + o_D, ws + o_m3, 256, 512);
  GEMM(64, 0, w_enc3, ws + o_D, nullptr, ws + o_E, 512, 64, 256 * 27, 8, 4, 0, 16);
  bnrelu(ws + o_E, ws + o_m4, 512, 64);

  // ---------------- bottleneck ----------------
  GEMM(64, 0, w_btd, ws + o_E, nullptr, ws + o_F, 1024, 8, 512 * 27, 4, 2, 0, 16);
  bnrelu(ws + o_F, ws + o_m5, 1024, 8);
  GEMM(64, 3, w_btc, ws + o_F, nullptr, ws + o_G, 1024, 8, 1024 * 27, 2, 2, 0, 32);
  bnrelu(ws + o_G, ws + o_m5, 1024, 8);

  // ---------------- decoder ----------------
  convTpar(w_up0, ws + o_G, ws + o_H, 512, 1024, 2, ws + o_A, 2097152);
  bnrelu(ws + o_H, ws + o_m4, 512, 64);
  GEMM(64, 2, w_fu0, ws + o_H, ws + o_E, ws + o_I, 512, 64, 1024, 4, 4, 512, 8);
  bnrelu(ws + o_I, ws + o_m4, 512, 64);

  convTpar(w_up1, ws + o_I, ws + o_J, 256, 512, 4, ws + o_A, 2097152);
  bnrelu(ws + o_J, ws + o_m3, 256, 512);
  GEMM(64, 2, w_fu1, ws + o_J, ws + o_D, ws + o_K, 256, 512, 512, 8, 8, 256, 4);
  bnrelu(ws + o_K, ws + o_m3, 256, 512);

  convTpar(w_up2, ws + o_K, ws + o_L, 128, 256, 8, ws + o_A, 2097152);
  bnrelu(ws + o_L, ws + o_m2, 128, 4096);
  GEMM(64, 2, w_fu2, ws + o_L, ws + o_C, ws + o_M, 128, 4096, 256, 16, 16, 128, 1);
  bnrelu(ws + o_M, ws + o_m2, 128, 4096);

  // up3 writes o_A; scratch uses the dead o_D..o_M gap
  convTpar(w_up3, ws + o_M, ws + o_A, 64, 128, 16, ws + o_D, 1032192);
  bnrelu(ws + o_A, ws + o_m1, 64, 32768);
  GEMM(64, 2, w_fu3, ws + o_A, ws + o_B, ws + o_N, 64, 32768, 128, 32, 32, 64, 1);
  bnrelu(ws + o_N, ws + o_m1, 64, 32768);

  // ---------------- final up (M=16): 8 parity classes, Z=1 direct ----------------
  for (int cls = 0; cls < 8; ++cls) {
    int px = cls & 1, py = (cls >> 1) & 1, pz = (cls >> 2) & 1;
    int T = 1 << ((1 - px) + (1 - py) + (1 - pz));
    int K = 64 * T;
    int nch = (K + 31) >> 5;
    dim3 g((32768 + 63) / 64, 1, 1);
    k_gemm<16, 4><<<g, TPB, 0, stream>>>(w_fin, ws + o_N, nullptr, ws + o_fin,
                                         16, 32768, K, 32, 32, cls, nch);
  }
  stats(ws + o_fin, ws + o_m0, 16, 262144);
  long total = 16L * 262144;
  k_apply_out<<<blocks(total), TPB, 0, stream>>>(ws + o_fin, ws + o_m0, st, out,
                                                 262144, total);
#undef GEMM
}

// Round 9
// 1492.481 us; speedup vs baseline: 3.7657x; 1.1227x over previous
//
#include <hip/hip_runtime.h>
#include <hip/hip_bf16.h>

#define TPB 256

// ================= masks =================
__global__ __launch_bounds__(TPB) void k_mask0(const float* __restrict__ mask,
                                               float* __restrict__ m0, int n) {
  int i = blockIdx.x * TPB + threadIdx.x;
  if (i < n) m0[i] = (mask[i] < 0.1f) ? 1.0f : 0.0f;
}

__global__ __launch_bounds__(TPB) void k_downmask(const float* __restrict__ mi,
                                                  float* __restrict__ mo, int Dout) {
  int n = Dout * Dout * Dout;
  int idx = blockIdx.x * TPB + threadIdx.x;
  if (idx >= n) return;
  int Din = Dout * 2;
  int ox = idx % Dout, oy = (idx / Dout) % Dout, oz = idx / (Dout * Dout);
  float v = 0.f;
  for (int kz = 0; kz < 3; kz++) {
    int iz = 2 * oz + kz - 1; if ((unsigned)iz >= (unsigned)Din) continue;
    for (int ky = 0; ky < 3; ky++) {
      int iy = 2 * oy + ky - 1; if ((unsigned)iy >= (unsigned)Din) continue;
      for (int kx = 0; kx < 3; kx++) {
        int ix = 2 * ox + kx - 1; if ((unsigned)ix >= (unsigned)Din) continue;
        v = fmaxf(v, mi[(iz * Din + iy) * Din + ix]);
      }
    }
  }
  mo[idx] = v;
}

__global__ __launch_bounds__(TPB) void k_maskx(const float* __restrict__ x,
                                               const float* __restrict__ m,
                                               float* __restrict__ o,
                                               long total, int vox) {
  long i = blockIdx.x * (long)TPB + threadIdx.x;
  if (i < total) o[i] = x[i] * m[i % vox];
}

__global__ __launch_bounds__(TPB) void k_sumparts(const float* __restrict__ parts,
                                                  float* __restrict__ out,
                                                  long n, int s) {
  long i = blockIdx.x * (long)TPB + threadIdx.x;
  if (i >= n) return;
  float a = 0.f;
  for (int j = 0; j < s; j++) a += parts[(long)j * n + i];
  out[i] = a;
}

// sum split-K partials of one parity class and scatter to full-grid layout
__global__ __launch_bounds__(TPB) void k_sumscat(const float* __restrict__ parts,
                                                 float* __restrict__ out,
                                                 int M, int Np, int Z, int Dh,
                                                 int lgDh, int cls) {
  long i = blockIdx.x * (long)TPB + threadIdx.x;
  long tot = (long)M * Np;
  if (i >= tot) return;
  int co = (int)(i >> (3 * lgDh));
  int pp = (int)(i & (Np - 1));
  float s = 0.f;
  for (int z = 0; z < Z; z++) s += parts[((long)z * M + co) * Np + pp];
  int px = cls & 1, py = (cls >> 1) & 1, pz = (cls >> 2) & 1;
  int ox = pp & (Dh - 1), oy = (pp >> lgDh) & (Dh - 1), oz = pp >> (2 * lgDh);
  int DF = Dh * 2;
  long fc = ((long)(2 * oz + pz) * DF + (2 * oy + py)) * DF + (2 * ox + px);
  out[(long)co * ((long)DF * DF * DF) + fc] = s;
}

// ================= tiled implicit-GEMM, split-K, reg-prefetch =================
// C[M][N] = A[M][K] x B[K][N]
// MODE 0: conv k3 s2 p1    (k=(ci,27taps); i = 2o + k - 1)
// MODE 2: 1x1 fuse over concat(B1[C1], B2[K-C1])
// MODE 3: conv k3 s1 p1    (i = o + k - 1)
// MODE 4: convT parity class. C1 = packed parity (pz<<2|py<<1|px).
template<int MT, int MODE>
__global__ __launch_bounds__(TPB) void k_gemm(const float* __restrict__ A,
                                              const float* __restrict__ B1,
                                              const float* __restrict__ B2,
                                              float* __restrict__ C,
                                              int M, int N, int K,
                                              int Din, int Dout, int C1,
                                              int kcPer) {
  constexpr int MR = MT / 16;
  constexpr int AEL = (MT == 64) ? 8 : 2;
  __shared__ __align__(16) float At[32][MT];
  __shared__ __align__(16) float Bt[32][64];

  const int t = threadIdx.x;
  const int n0 = blockIdx.x * 64;
  const int m0 = blockIdx.y * MT;

  const int p0 = (t & 15) * 4;
  const int co0 = (t >> 4) * MR;

  const int pb = t & 63;
  const int kb0 = (t >> 6) * 8;
  const int pp = n0 + pb;
  const int oxb = pp & (Dout - 1);
  const int oyb = (pp / Dout) & (Dout - 1);
  const int ozb = pp / (Dout * Dout);

  int px = 0, py = 0, pz = 0, lgnx = 0, lgny = 0, lgT = 0, Cin = 0;
  if (MODE == 4) {
    px = C1 & 1; py = (C1 >> 1) & 1; pz = (C1 >> 2) & 1;
    lgnx = 1 - px; lgny = 1 - py;
    lgT = lgnx + lgny + (1 - pz);
    Cin = K >> lgT;
  }

  const int nch = (K + 31) >> 5;
  const int c0 = blockIdx.z * kcPer;
  int c1 = c0 + kcPer; if (c1 > nch) c1 = nch;

  float acc[MR][4];
#pragma unroll
  for (int a = 0; a < MR; a++)
#pragma unroll
    for (int b = 0; b < 4; b++) acc[a][b] = 0.f;

  float raf[AEL];
  float rb[8];
  const int co_a = (MT == 64) ? (t >> 2) : (t & 15);
  const int ka   = (MT == 64) ? ((t & 3) * 8) : ((t >> 4) * 2);
  const long arow = (long)(m0 + co_a) * K;

  auto loadA = [&](int c) {
    const int k0 = c << 5;
    if (MODE == 4) {
#pragma unroll
      for (int j = 0; j < AEL; j++) {
        const int kg = k0 + ka + j;
        float v = 0.f;
        if (kg < K) {
          int ci = kg >> lgT;
          int tt = kg & ((1 << lgT) - 1);
          int tx = tt & ((1 << lgnx) - 1); tt >>= lgnx;
          int ty = tt & ((1 << lgny) - 1);
          int tz = tt >> lgny;
          int kx = px ? 1 : (tx << 1);
          int ky = py ? 1 : (ty << 1);
          int kz = pz ? 1 : (tz << 1);
          v = A[((long)(m0 + co_a) * Cin + ci) * 27 + (kz * 3 + ky) * 3 + kx];
        }
        raf[j] = v;
      }
    } else if (MT == 64) {
#pragma unroll
      for (int j = 0; j < 2; j++) {
        const int kg = k0 + ka + j * 4;
        float4 v = (kg < K) ? *(const float4*)&A[arow + kg]
                            : make_float4(0.f, 0.f, 0.f, 0.f);
        raf[j * 4 + 0] = v.x; raf[j * 4 + 1] = v.y;
        raf[j * 4 + 2] = v.z; raf[j * 4 + 3] = v.w;
      }
    } else {
      const int kg = k0 + ka;
      raf[0] = (kg < K) ? A[arow + kg] : 0.f;
      raf[1] = (kg + 1 < K) ? A[arow + kg + 1] : 0.f;
    }
  };

  auto loadB = [&](int c) {
    const int k0 = c << 5;
#pragma unroll
    for (int j = 0; j < 8; j++) {
      const int kg = k0 + kb0 + j;
      float v = 0.f;
      if (kg < K && pp < N) {
        if (MODE == 2) {
          v = (kg < C1) ? B1[(long)kg * N + pp] : B2[(long)(kg - C1) * N + pp];
        } else if (MODE == 4) {
          int ci = kg >> lgT;
          int tt = kg & ((1 << lgT) - 1);
          int tx = tt & ((1 << lgnx) - 1); tt >>= lgnx;
          int ty = tt & ((1 << lgny) - 1);
          int tz = tt >> lgny;
          int ix = px ? oxb : (oxb - 1 + tx);
          int iy = py ? oyb : (oyb - 1 + ty);
          int iz = pz ? ozb : (ozb - 1 + tz);
          if ((ix | iy | iz) >= 0)
            v = B1[(long)ci * Din * Din * Din + ((long)iz * Din + iy) * Din + ix];
        } else {
          const int ci = kg / 27;
          const int tap = kg - ci * 27;
          const int kz = tap / 9;
          const int r9 = tap - kz * 9;
          const int ky = r9 / 3;
          const int kx = r9 - ky * 3;
          int iz, iy, ix;
          bool ok;
          if (MODE == 0) {
            iz = 2 * ozb + kz - 1; iy = 2 * oyb + ky - 1; ix = 2 * oxb + kx - 1;
            ok = (unsigned)iz < (unsigned)Din && (unsigned)iy < (unsigned)Din &&
                 (unsigned)ix < (unsigned)Din;
          } else { // MODE 3
            iz = ozb + kz - 1; iy = oyb + ky - 1; ix = oxb + kx - 1;
            ok = (unsigned)iz < (unsigned)Din && (unsigned)iy < (unsigned)Din &&
                 (unsigned)ix < (unsigned)Din;
          }
          if (ok)
            v = B1[(long)ci * Din * Din * Din + ((long)iz * Din + iy) * Din + ix];
        }
      }
      rb[j] = v;
    }
  };

  if (c0 < c1) { loadA(c0); loadB(c0); }

  for (int c = c0; c < c1; ++c) {
    __syncthreads();
#pragma unroll
    for (int j = 0; j < AEL; j++) At[ka + j][co_a] = raf[j];
#pragma unroll
    for (int j = 0; j < 8; j++) Bt[kb0 + j][pb] = rb[j];
    if (c + 1 < c1) { loadA(c + 1); loadB(c + 1); }
    __syncthreads();
#pragma unroll
    for (int kk = 0; kk < 32; ++kk) {
      const float4 b4 = *(const float4*)&Bt[kk][p0];
      if (MR == 4) {
        const float4 a4 = *(const float4*)&At[kk][co0];
        acc[0][0] += a4.x * b4.x; acc[0][1] += a4.x * b4.y;
        acc[0][2] += a4.x * b4.z; acc[0][3] += a4.x * b4.w;
        acc[1][0] += a4.y * b4.x; acc[1][1] += a4.y * b4.y;
        acc[1][2] += a4.y * b4.z; acc[1][3] += a4.y * b4.w;
        acc[2][0] += a4.z * b4.x; acc[2][1] += a4.z * b4.y;
        acc[2][2] += a4.z * b4.z; acc[2][3] += a4.z * b4.w;
        acc[3][0] += a4.w * b4.x; acc[3][1] += a4.w * b4.y;
        acc[3][2] += a4.w * b4.z; acc[3][3] += a4.w * b4.w;
      } else {
        const float a = At[kk][co0];
        acc[0][0] += a * b4.x; acc[0][1] += a * b4.y;
        acc[0][2] += a * b4.z; acc[0][3] += a * b4.w;
      }
    }
  }

  if (MODE == 4 && gridDim.z == 1) {
    const int lgD = 31 - __clz(Dout);
    const int DF = Din << 1;
    const long voxF = (long)DF * DF * DF;
#pragma unroll
    for (int mr = 0; mr < MR; mr++) {
#pragma unroll
      for (int e = 0; e < 4; e++) {
        int pp2 = n0 + p0 + e;
        if (pp2 < N) {
          int ox = pp2 & (Dout - 1), oy = (pp2 >> lgD) & (Dout - 1),
              oz = pp2 >> (2 * lgD);
          long fc = ((long)(2 * oz + pz) * DF + (2 * oy + py)) * DF +
                    (2 * ox + px);
          C[(long)(m0 + co0 + mr) * voxF + fc] = acc[mr][e];
        }
      }
    }
  } else {
    float* Cz = C + (long)blockIdx.z * ((long)M * N);
#pragma unroll
    for (int mr = 0; mr < MR; mr++) {
      if (n0 + p0 < N) {
        float4 v = make_float4(acc[mr][0], acc[mr][1], acc[mr][2], acc[mr][3]);
        *(float4*)&Cz[(long)(m0 + co0 + mr) * N + n0 + p0] = v;
      }
    }
  }
}

// ================= hierarchical masked BN stats =================
__global__ __launch_bounds__(TPB) void k_stats1(const float* __restrict__ a,
                                                const float* __restrict__ m,
                                                float* __restrict__ part,
                                                float* __restrict__ partM,
                                                int vox, int chunk) {
  const int s = blockIdx.x, c = blockIdx.y;
  const float* ap = a + (long)c * vox + (long)s * chunk;
  const float* mp = m + (long)s * chunk;
  float s0 = 0.f, s1 = 0.f, sm = 0.f;
  for (int i = threadIdx.x; i < chunk; i += TPB) {
    float mv = mp[i];
    float v = ap[i] * mv;
    s0 += v; s1 += v * v; sm += mv;
  }
  __shared__ float sh0[TPB], sh1[TPB], sh2[TPB];
  sh0[threadIdx.x] = s0; sh1[threadIdx.x] = s1; sh2[threadIdx.x] = sm;
  __syncthreads();
  for (int off = TPB / 2; off > 0; off >>= 1) {
    if (threadIdx.x < off) {
      sh0[threadIdx.x] += sh0[threadIdx.x + off];
      sh1[threadIdx.x] += sh1[threadIdx.x + off];
      sh2[threadIdx.x] += sh2[threadIdx.x + off];
    }
    __syncthreads();
  }
  if (threadIdx.x == 0) {
    const int S = gridDim.x;
    part[(c * S + s) * 2] = sh0[0];
    part[(c * S + s) * 2 + 1] = sh1[0];
    if (c == 0) partM[s] = sh2[0];
  }
}

__global__ __launch_bounds__(64) void k_stats2(const float* __restrict__ part,
                                               const float* __restrict__ partM,
                                               float* __restrict__ stats, int S) {
  const int c = blockIdx.x, t = threadIdx.x;
  float s0 = 0.f, s1 = 0.f, sm = 0.f;
  for (int s = t; s < S; s += 64) {
    s0 += part[(c * S + s) * 2];
    s1 += part[(c * S + s) * 2 + 1];
    sm += partM[s];
  }
  for (int off = 32; off > 0; off >>= 1) {
    s0 += __shfl_down(s0, off);
    s1 += __shfl_down(s1, off);
    sm += __shfl_down(sm, off);
  }
  if (t == 0) {
    float n = fmaxf(sm, 1.f);
    float mu = s0 / n;
    float var = fmaxf(s1 / n - mu * mu, 0.f);
    stats[2 * c] = mu;
    stats[2 * c + 1] = rsqrtf(var + 1e-5f);
  }
}

__global__ __launch_bounds__(TPB) void k_apply(float* __restrict__ a,
                                               const float* __restrict__ m,
                                               const float* __restrict__ stats,
                                               int vox, long total) {
  long idx = blockIdx.x * (long)TPB + threadIdx.x;
  if (idx >= total) return;
  int c = (int)(idx / vox);
  int p = (int)(idx % vox);
  float v = (a[idx] - stats[2 * c]) * stats[2 * c + 1];
  a[idx] = fmaxf(v, 0.f) * m[p];
}

__global__ __launch_bounds__(TPB) void k_apply_out(const float* __restrict__ a,
                                                   const float* __restrict__ m,
                                                   const float* __restrict__ stats,
                                                   float* __restrict__ out,
                                                   int vox, long total) {
  long idx = blockIdx.x * (long)TPB + threadIdx.x;
  if (idx >= total) return;
  int c = (int)(idx / vox);
  int p = (int)(idx % vox);
  float v = (a[idx] - stats[2 * c]) * stats[2 * c + 1];
  out[idx] = fmaxf(v, 0.f) * m[p];
}

// ================= workspace layout (floats) =================
constexpr long o_m0 = 0;          // 64^3
constexpr long o_m1 = 262144;     // 32^3
constexpr long o_m2 = 294912;     // 16^3
constexpr long o_m3 = 299008;     // 8^3
constexpr long o_m4 = 299520;     // 4^3
constexpr long o_m5 = 299584;     // 2^3
constexpr long o_st = 299592;     // 2048 stats
constexpr long o_A  = 301696;     // 2M: xm -> split-K scratch -> u3 -> final preact
constexpr long o_B  = 2398848;    // 2M: a0 (feats0)
constexpr long o_C  = 4496000;    // 512K: a1 (feats1)
constexpr long o_D  = 5020288;    // 128K: a2 (feats2)
constexpr long o_E  = 5151360;    // 32K: a3 (feats3)
constexpr long o_F  = 5184128;    // 8K: a4
constexpr long o_G  = 5192320;    // 8K: a5
constexpr long o_H  = 5200512;    // 32K: u0
constexpr long o_I  = 5233280;    // 32K: f0
constexpr long o_J  = 5266048;    // 128K: u1
constexpr long o_K  = 5397120;    // 128K: f1
constexpr long o_L  = 5528192;    // 512K: u2
constexpr long o_M  = 6052480;    // 512K: f2
constexpr long o_N  = 6576768;    // 2M: f3 (dead until fu3 -> up3 scratch)
constexpr long o_P  = 8673920;    // 16K: BN partials
constexpr long o_PM = 8690304;    // 64: mask-count partials
constexpr long o_fin = o_A;       // 4M: final preact overlays A+B (both dead)

extern "C" void kernel_launch(void* const* d_in, const int* in_sizes, int n_in,
                              void* d_out, int out_size, void* d_ws, size_t ws_size,
                              hipStream_t stream) {
  const float* x      = (const float*)d_in[0];
  const float* mask   = (const float*)d_in[1];
  const float* w_enc0 = (const float*)d_in[2];
  const float* w_enc1 = (const float*)d_in[3];
  const float* w_enc2 = (const float*)d_in[4];
  const float* w_enc3 = (const float*)d_in[5];
  const float* w_btd  = (const float*)d_in[6];
  const float* w_btc  = (const float*)d_in[7];
  const float* w_up0  = (const float*)d_in[8];
  const float* w_fu0  = (const float*)d_in[9];
  const float* w_up1  = (const float*)d_in[10];
  const float* w_fu1  = (const float*)d_in[11];
  const float* w_up2  = (const float*)d_in[12];
  const float* w_fu2  = (const float*)d_in[13];
  const float* w_up3  = (const float*)d_in[14];
  const float* w_fu3  = (const float*)d_in[15];
  const float* w_fin  = (const float*)d_in[16];

  float* ws = (float*)d_ws;
  float* st = ws + o_st;
  float* out = (float*)d_out;

  auto blocks = [](long n) { return (unsigned)((n + TPB - 1) / TPB); };

  // masks
  k_mask0<<<blocks(262144), TPB, 0, stream>>>(mask, ws + o_m0, 262144);
  k_downmask<<<blocks(32768), TPB, 0, stream>>>(ws + o_m0, ws + o_m1, 32);
  k_downmask<<<blocks(4096), TPB, 0, stream>>>(ws + o_m1, ws + o_m2, 16);
  k_downmask<<<blocks(512), TPB, 0, stream>>>(ws + o_m2, ws + o_m3, 8);
  k_downmask<<<blocks(64), TPB, 0, stream>>>(ws + o_m3, ws + o_m4, 4);
  k_downmask<<<blocks(8), TPB, 0, stream>>>(ws + o_m4, ws + o_m5, 2);

  // masked input -> A
  k_maskx<<<blocks(8L * 262144), TPB, 0, stream>>>(x, ws + o_m0, ws + o_A,
                                                   8L * 262144, 262144);

  auto stats = [&](const float* a, const float* m, int C, int vox) {
    int S = vox / TPB; if (S < 1) S = 1; if (S > 64) S = 64;
    int chunk = vox / S;
    dim3 g(S, C);
    k_stats1<<<g, TPB, 0, stream>>>(a, m, ws + o_P, ws + o_PM, vox, chunk);
    k_stats2<<<C, 64, 0, stream>>>(ws + o_P, ws + o_PM, st, S);
  };
  auto bnrelu = [&](float* a, const float* m, int C, int vox) {
    stats(a, m, C, vox);
    long total = (long)C * vox;
    k_apply<<<blocks(total), TPB, 0, stream>>>(a, m, st, vox, total);
  };

#define GEMM(MT, MODE, A_, B1_, B2_, O_, M_, N_, K_, DIN_, DOUT_, C1_, Z_)   \
  do {                                                                        \
    int nch_ = ((K_) + 31) >> 5;                                              \
    int kper_ = (nch_ + (Z_) - 1) / (Z_);                                     \
    dim3 g_(((N_) + 63) / 64, (M_) / (MT), (Z_));                             \
    float* dst_ = ((Z_) > 1) ? (ws + o_A) : (O_);                             \
    k_gemm<MT, MODE><<<g_, TPB, 0, stream>>>(A_, B1_, B2_, dst_, M_, N_, K_,  \
                                             DIN_, DOUT_, C1_, kper_);        \
    if ((Z_) > 1)                                                             \
      k_sumparts<<<blocks((long)(M_) * (N_)), TPB, 0, stream>>>(              \
          ws + o_A, O_, (long)(M_) * (N_), (Z_));                             \
  } while (0)

  // parity-decomposed convT: 8 classes, each a dense shift-only GEMM
  auto convTpar = [&](const float* w, const float* in, float* o, int M, int Cin,
                      int Dh, float* scr, long scrCap) {
    int lgDh = 31 - __builtin_clz(Dh);
    int Np = Dh * Dh * Dh;
    for (int cls = 0; cls < 8; ++cls) {
      int px = cls & 1, py = (cls >> 1) & 1, pz = (cls >> 2) & 1;
      int T = 1 << ((1 - px) + (1 - py) + (1 - pz));
      int K = Cin * T;
      int nch = (K + 31) >> 5;
      long cap = scrCap / ((long)M * Np);
      int Z = nch; if (Z > cap) Z = (int)cap; if (Z > 128) Z = 128;
      if (Z < 1) Z = 1;
      int kper = (nch + Z - 1) / Z;
      dim3 g((Np + 63) / 64, M / 64, Z);
      if (Z == 1) {
        k_gemm<64, 4><<<g, TPB, 0, stream>>>(w, in, nullptr, o, M, Np, K,
                                             Dh, Dh, cls, kper);
      } else {
        k_gemm<64, 4><<<g, TPB, 0, stream>>>(w, in, nullptr, scr, M, Np, K,
                                             Dh, Dh, cls, kper);
        k_sumscat<<<blocks((long)M * Np), TPB, 0, stream>>>(scr, o, M, Np, Z,
                                                            Dh, lgDh, cls);
      }
    }
  };

  // ---------------- encoder ----------------
  GEMM(64, 0, w_enc0, ws + o_A, nullptr, ws + o_B, 64, 32768, 8 * 27, 64, 32, 0, 1);
  bnrelu(ws + o_B, ws + o_m1, 64, 32768);
  GEMM(64, 0, w_enc1, ws + o_B, nullptr, ws + o_C, 128, 4096, 64 * 27, 32, 16, 0, 4);
  bnrelu(ws + o_C, ws + o_m2, 128, 4096);
  GEMM(64, 0, w_enc2, ws + o_C, nullptr, ws + o_D, 256, 512, 128 * 27, 16, 8, 0, 16);
  bnrelu(ws + o_D, ws + o_m3, 256, 512);
  GEMM(64, 0, w_enc3, ws + o_D, nullptr, ws + o_E, 512, 64, 256 * 27, 8, 4, 0, 64);
  bnrelu(ws + o_E, ws + o_m4, 512, 64);

  // ---------------- bottleneck ----------------
  GEMM(64, 0, w_btd, ws + o_E, nullptr, ws + o_F, 1024, 8, 512 * 27, 4, 2, 0, 108);
  bnrelu(ws + o_F, ws + o_m5, 1024, 8);
  GEMM(64, 3, w_btc, ws + o_F, nullptr, ws + o_G, 1024, 8, 1024 * 27, 2, 2, 0, 108);
  bnrelu(ws + o_G, ws + o_m5, 1024, 8);

  // ---------------- decoder ----------------
  convTpar(w_up0, ws + o_G, ws + o_H, 512, 1024, 2, ws + o_A, 2097152);
  bnrelu(ws + o_H, ws + o_m4, 512, 64);
  GEMM(64, 2, w_fu0, ws + o_H, ws + o_E, ws + o_I, 512, 64, 1024, 4, 4, 512, 32);
  bnrelu(ws + o_I, ws + o_m4, 512, 64);

  convTpar(w_up1, ws + o_I, ws + o_J, 256, 512, 4, ws + o_A, 2097152);
  bnrelu(ws + o_J, ws + o_m3, 256, 512);
  GEMM(64, 2, w_fu1, ws + o_J, ws + o_D, ws + o_K, 256, 512, 512, 8, 8, 256, 16);
  bnrelu(ws + o_K, ws + o_m3, 256, 512);

  convTpar(w_up2, ws + o_K, ws + o_L, 128, 256, 8, ws + o_A, 2097152);
  bnrelu(ws + o_L, ws + o_m2, 128, 4096);
  GEMM(64, 2, w_fu2, ws + o_L, ws + o_C, ws + o_M, 128, 4096, 256, 16, 16, 128, 2);
  bnrelu(ws + o_M, ws + o_m2, 128, 4096);

  // up3 writes o_A; scratch = o_N (f3 not yet written -> dead here)
  convTpar(w_up3, ws + o_M, ws + o_A, 64, 128, 16, ws + o_N, 2097152);
  bnrelu(ws + o_A, ws + o_m1, 64, 32768);
  GEMM(64, 2, w_fu3, ws + o_A, ws + o_B, ws + o_N, 64, 32768, 128, 32, 32, 64, 1);
  bnrelu(ws + o_N, ws + o_m1, 64, 32768);

  // ---------------- final up (M=16): 8 parity classes, Z=1 direct ----------------
  for (int cls = 0; cls < 8; ++cls) {
    int px = cls & 1, py = (cls >> 1) & 1, pz = (cls >> 2) & 1;
    int T = 1 << ((1 - px) + (1 - py) + (1 - pz));
    int K = 64 * T;
    int nch = (K + 31) >> 5;
    dim3 g((32768 + 63) / 64, 1, 1);
    k_gemm<16, 4><<<g, TPB, 0, stream>>>(w_fin, ws + o_N, nullptr, ws + o_fin,
                                         16, 32768, K, 32, 32, cls, nch);
  }
  stats(ws + o_fin, ws + o_m0, 16, 262144);
  long total = 16L * 262144;
  k_apply_out<<<blocks(total), TPB, 0, stream>>>(ws + o_fin, ws + o_m0, st, out,
                                                 262144, total);
#undef GEMM
}